// Round 1
// baseline (1147.674 us; speedup 1.0000x reference)
//
#include <hip/hip_runtime.h>
#include <hip/hip_bf16.h>
#include <math.h>

#define Nn 10000
#define Ee 160000
#define ET 170000   // Ee + Nn (self loops)
#define LL 6

// ---------------- node embedding: h = x @ node_w + node_b ----------------
__global__ void k_node_embed(const float* __restrict__ x, const float* __restrict__ nw,
                             const float* __restrict__ nb, float* __restrict__ h) {
    int idx = blockIdx.x * 256 + threadIdx.x;
    if (idx >= Nn * 128) return;
    int n = idx >> 7, c = idx & 127;
    const float* xr = x + (size_t)n * 8;
    float acc = nb[c];
#pragma unroll
    for (int k = 0; k < 8; k++) acc += xr[k] * nw[k * 128 + c];
    h[idx] = acc;
}

// ---------------- small precompute: vnf_row, d1, M1 ----------------
// M1 = ea_proj_w @ att1_w[:128]   (4x128)
// d1 = ea_proj_b@W1a + vnf_row@W1b + att1_b   (128)
__global__ void k_small(const float* __restrict__ vnfc, const float* __restrict__ vw,
                        const float* __restrict__ vb, const float* __restrict__ eab,
                        const float* __restrict__ a1w, const float* __restrict__ a1b,
                        const float* __restrict__ eaw, float* __restrict__ M1,
                        float* __restrict__ d1) {
    __shared__ float vr[128];
    int t = threadIdx.x;
    if (t < 128) {
        float a = vb[t];
#pragma unroll
        for (int k = 0; k < 6; k++) a += vnfc[k] * vw[k * 128 + t];
        vr[t] = a;
    }
    __syncthreads();
    if (t < 128) {
        float a = a1b[t];
        for (int k = 0; k < 128; k++) a += eab[k] * a1w[k * 128 + t];
        for (int k = 0; k < 128; k++) a += vr[k] * a1w[(128 + k) * 128 + t];
        d1[t] = a;
    }
    {
        int r = t >> 7, j = t & 127;   // t < 512 -> r in [0,4)
        float a = 0.f;
        for (int k = 0; k < 128; k++) a += eaw[r * 128 + k] * a1w[k * 128 + j];
        M1[r * 128 + j] = a;
    }
}

// ---------------- B matrices: Bs/Bd/Be [L][128][4] ----------------
__global__ void k_bmat(const float* __restrict__ glw, const float* __restrict__ gas,
                       const float* __restrict__ gad, const float* __restrict__ glew,
                       const float* __restrict__ gae, float* __restrict__ Bs,
                       float* __restrict__ Bd, float* __restrict__ Be) {
    int idx = blockIdx.x * 256 + threadIdx.x;
    if (idx >= LL * 128 * 4) return;
    int hh = idx & 3, k = (idx >> 2) & 127, l = idx >> 9;
    const float* lwp = glw  + (size_t)l * 65536 + k * 512 + hh * 128;
    const float* lep = glew + (size_t)l * 65536 + k * 512 + hh * 128;
    const float* sp = gas + l * 512 + hh * 128;
    const float* dp = gad + l * 512 + hh * 128;
    const float* ep = gae + l * 512 + hh * 128;
    float s1 = 0, s2 = 0, s3 = 0;
    for (int c = 0; c < 128; c++) {
        float lv = lwp[c];
        s1 += lv * sp[c];
        s2 += lv * dp[c];
        s3 += lep[c] * ep[c];
    }
    Bs[idx] = s1; Bd[idx] = s2; Be[idx] = s3;
}

// ---------------- edge MLP (gate) + al_e for all 6 layers + w_edge sum ----------------
__global__ __launch_bounds__(64) void k_edge_mlp(
    const float* __restrict__ ea, const float* __restrict__ M1, const float* __restrict__ d1,
    const float* __restrict__ a2w, const float* __restrict__ a2b,
    const float* __restrict__ a3w, const float* __restrict__ a3b,
    const float* __restrict__ eaw, const float* __restrict__ eab,
    const float* __restrict__ Be, float* __restrict__ ale, float* __restrict__ wsum) {
    __shared__ float a1s[128];
    __shared__ float wes[128];
    int lane = threadIdx.x;
    // hoisted per-lane constants
    float m10 = M1[lane],      m11 = M1[128 + lane], m12 = M1[256 + lane], m13 = M1[384 + lane];
    float m20 = M1[64 + lane], m21 = M1[192 + lane], m22 = M1[320 + lane], m23 = M1[448 + lane];
    float dd0 = d1[lane], dd1 = d1[64 + lane];
    float q10 = eaw[lane],      q11 = eaw[128 + lane], q12 = eaw[256 + lane], q13 = eaw[384 + lane];
    float q20 = eaw[64 + lane], q21 = eaw[192 + lane], q22 = eaw[320 + lane], q23 = eaw[448 + lane];
    float qb0 = eab[lane], qb1 = eab[64 + lane];
    float b2l = a2b[lane];
    float w3l = a3w[lane];
    float b3 = a3b[0];
    float accw0 = 0.f, accw1 = 0.f;
    for (int e = blockIdx.x; e < Ee; e += gridDim.x) {
        float e0 = ea[e * 4 + 0], e1 = ea[e * 4 + 1], e2v = ea[e * 4 + 2], e3 = ea[e * 4 + 3];
        float p0 = dd0 + e0 * m10 + e1 * m11 + e2v * m12 + e3 * m13;
        float p1 = dd1 + e0 * m20 + e1 * m21 + e2v * m22 + e3 * m23;
        a1s[lane]      = fmaxf(p0, 0.f);
        a1s[lane + 64] = fmaxf(p1, 0.f);
        __syncthreads();   // A
        const float4* a1v = (const float4*)a1s;
        float s0 = 0, s1 = 0, s2 = 0, s3 = 0;
#pragma unroll 8
        for (int kb = 0; kb < 32; kb++) {
            float4 av = a1v[kb];
            s0 += av.x * a2w[(4 * kb + 0) * 64 + lane];
            s1 += av.y * a2w[(4 * kb + 1) * 64 + lane];
            s2 += av.z * a2w[(4 * kb + 2) * 64 + lane];
            s3 += av.w * a2w[(4 * kb + 3) * 64 + lane];
        }
        float a2 = fmaxf(b2l + s0 + s1 + s2 + s3, 0.f);
        float pr = a2 * w3l;
#pragma unroll
        for (int d = 32; d > 0; d >>= 1) pr += __shfl_down(pr, d);
        float g = __shfl(pr, 0);
        g = 1.f / (1.f + __expf(-(g + b3)));
        float f0 = qb0 + e0 * q10 + e1 * q11 + e2v * q12 + e3 * q13;
        float f1 = qb1 + e0 * q20 + e1 * q21 + e2v * q22 + e3 * q23;
        float w0 = f0 * g, w1 = f1 * g;
        wes[lane] = w0; wes[lane + 64] = w1;
        accw0 += w0; accw1 += w1;
        __syncthreads();   // B
        if (lane < 24) {
            int l = lane >> 2, hh = lane & 3;
            const float* bp = Be + l * 512 + hh;
            const float4* wv4 = (const float4*)wes;
            float t0 = 0, t1 = 0, t2 = 0, t3 = 0;
#pragma unroll 8
            for (int kb = 0; kb < 32; kb++) {
                float4 wv = wv4[kb];
                t0 += wv.x * bp[(4 * kb + 0) * 4];
                t1 += wv.y * bp[(4 * kb + 1) * 4];
                t2 += wv.z * bp[(4 * kb + 2) * 4];
                t3 += wv.w * bp[(4 * kb + 3) * 4];
            }
            ale[(size_t)e * 24 + lane] = t0 + t1 + t2 + t3;
        }
    }
    atomicAdd(&wsum[lane], accw0);
    atomicAdd(&wsum[lane + 64], accw1);
}

// ---------------- loop-edge al_e (from mean w_edge) ----------------
__global__ void k_loop_ale(const float* __restrict__ wsum, const float* __restrict__ Be,
                           float* __restrict__ lale) {
    int t = threadIdx.x;
    if (t >= 24) return;
    int l = t >> 2, hh = t & 3;
    const float* bp = Be + l * 512 + hh;
    float s = 0;
    for (int k = 0; k < 128; k++) s += wsum[k] * bp[k * 4];
    lale[t] = s * (1.0f / Ee);
}

// ---------------- counting sort by dst: hist / scan / scatter ----------------
__global__ void k_hist(const int* __restrict__ ei, int* __restrict__ hist) {
    int i = blockIdx.x * 256 + threadIdx.x;
    if (i >= ET) return;
    int d = (i < Ee) ? ei[Ee + i] : (i - Ee);
    atomicAdd(&hist[d], 1);
}

__global__ __launch_bounds__(1024) void k_scan(const int* __restrict__ hist,
                                               int* __restrict__ seg, int* __restrict__ pos) {
    __shared__ int wsums[16];
    __shared__ int carry_s;
    int t = threadIdx.x;
    int lane = t & 63, wid = t >> 6;
    if (t == 0) { carry_s = 0; seg[0] = 0; }
    __syncthreads();
    for (int base = 0; base < Nn; base += 1024) {
        int idx = base + t;
        int v = (idx < Nn) ? hist[idx] : 0;
        int sc = v;
#pragma unroll
        for (int d = 1; d < 64; d <<= 1) {
            int up = __shfl_up(sc, d);
            if (lane >= d) sc += up;
        }
        if (lane == 63) wsums[wid] = sc;
        __syncthreads();
        if (wid == 0) {
            int wv = (lane < 16) ? wsums[lane] : 0;
            int wsc = wv;
#pragma unroll
            for (int d = 1; d < 16; d <<= 1) {
                int up = __shfl_up(wsc, d);
                if (lane >= d) wsc += up;
            }
            if (lane < 16) wsums[lane] = wsc - wv;   // exclusive wave offsets
        }
        __syncthreads();
        int carry = carry_s;
        int inc = sc + wsums[wid] + carry;
        if (idx < Nn) { seg[idx + 1] = inc; pos[idx] = inc - v; }
        __syncthreads();
        if (t == 1023) carry_s = inc;
        __syncthreads();
    }
}

__global__ void k_scatter(const int* __restrict__ ei, int* __restrict__ pos,
                          int* __restrict__ peid, int* __restrict__ psrc) {
    int i = blockIdx.x * 256 + threadIdx.x;
    if (i >= ET) return;
    int s, d;
    if (i < Ee) { s = ei[i]; d = ei[Ee + i]; } else { s = d = i - Ee; }
    int idx = atomicAdd(&pos[d], 1);
    peid[idx] = i;
    psrc[idx] = s;
}

// ---------------- per-layer: xh = h @ lw ; als/ald = h @ Bs/Bd ----------------
__global__ __launch_bounds__(256) void k_xh(
    const float* __restrict__ h, const float* __restrict__ lw,
    const float* __restrict__ Bs, const float* __restrict__ Bd,
    float* __restrict__ xh, float* __restrict__ als, float* __restrict__ ald) {
    __shared__ float4 hs4[16][32];
    int t = threadIdx.x;
    int n0 = blockIdx.x * 16;
    for (int z = t; z < 512; z += 256) {
        int i = z >> 5, kb = z & 31;
        hs4[i][kb] = *(const float4*)(h + (size_t)(n0 + i) * 128 + 4 * kb);
    }
    __syncthreads();
    int g = t >> 7;             // node group 0/1
    int c4 = (t & 127) * 4;     // col base (covers 512 cols)
    const float* lwc = lw + c4;
    float4 acc[8];
#pragma unroll
    for (int i = 0; i < 8; i++) acc[i] = make_float4(0.f, 0.f, 0.f, 0.f);
    for (int kb = 0; kb < 32; kb++) {
        float4 w0 = *(const float4*)(lwc + (size_t)(4 * kb + 0) * 512);
        float4 w1 = *(const float4*)(lwc + (size_t)(4 * kb + 1) * 512);
        float4 w2 = *(const float4*)(lwc + (size_t)(4 * kb + 2) * 512);
        float4 w3 = *(const float4*)(lwc + (size_t)(4 * kb + 3) * 512);
#pragma unroll
        for (int i = 0; i < 8; i++) {
            float4 hv = hs4[g * 8 + i][kb];
            acc[i].x += hv.x * w0.x + hv.y * w1.x + hv.z * w2.x + hv.w * w3.x;
            acc[i].y += hv.x * w0.y + hv.y * w1.y + hv.z * w2.y + hv.w * w3.y;
            acc[i].z += hv.x * w0.z + hv.y * w1.z + hv.z * w2.z + hv.w * w3.z;
            acc[i].w += hv.x * w0.w + hv.y * w1.w + hv.z * w2.w + hv.w * w3.w;
        }
    }
#pragma unroll
    for (int i = 0; i < 8; i++)
        *(float4*)(xh + (size_t)(n0 + g * 8 + i) * 512 + c4) = acc[i];
    if (t < 64) {
        int i = t >> 2, hh = t & 3;
        float s1 = 0, s2 = 0;
        for (int kb = 0; kb < 32; kb++) {
            float4 hv = hs4[i][kb];
            s1 += hv.x * Bs[(4 * kb + 0) * 4 + hh] + hv.y * Bs[(4 * kb + 1) * 4 + hh]
                + hv.z * Bs[(4 * kb + 2) * 4 + hh] + hv.w * Bs[(4 * kb + 3) * 4 + hh];
            s2 += hv.x * Bd[(4 * kb + 0) * 4 + hh] + hv.y * Bd[(4 * kb + 1) * 4 + hh]
                + hv.z * Bd[(4 * kb + 2) * 4 + hh] + hv.w * Bd[(4 * kb + 3) * 4 + hh];
        }
        als[(n0 + i) * 4 + hh] = s1;
        ald[(n0 + i) * 4 + hh] = s2;
    }
}

// ---------------- per-layer: alpha_partial (sorted order) = als[src] + al_e ----------------
__global__ void k_alpha(const int* __restrict__ peid, const int* __restrict__ psrc,
                        const float* __restrict__ als, const float* __restrict__ ale,
                        const float* __restrict__ lale, int l, float* __restrict__ alphap) {
    int i = blockIdx.x * 256 + threadIdx.x;
    if (i >= ET) return;
    int e = peid[i], s = psrc[i];
    float4 a = *(const float4*)(als + (size_t)s * 4);
    float4 b;
    if (e < Ee) b = *(const float4*)(ale + (size_t)e * 24 + l * 4);
    else        b = *(const float4*)(lale + l * 4);
    float4 o;
    o.x = a.x + b.x; o.y = a.y + b.y; o.z = a.z + b.z; o.w = a.w + b.w;
    *(float4*)(alphap + (size_t)i * 4) = o;
}

// ---------------- per-layer: segment softmax + gather-aggregate + LN (one block / node) ----
__global__ __launch_bounds__(256) void k_agg(
    const float* __restrict__ alphap, const int* __restrict__ psrc,
    const int* __restrict__ seg, const float* __restrict__ xh,
    const float* __restrict__ ald, const float* __restrict__ bias,
    const float* __restrict__ lnsc, const float* __restrict__ lnbi,
    float* __restrict__ hio) {
    __shared__ float rm[256], rs[256];
    __shared__ float wl[512];
    __shared__ float mh[4], inv[4];
    __shared__ int sl[128];
    int n = blockIdx.x, t = threadIdx.x;
    int start = seg[n], end = seg[n + 1];
    int hh = t & 3, slot = t >> 2;
    float aldh = ald[n * 4 + hh];
    // phase 1: online (max, sumexp) per head, strided over the segment
    float m = -INFINITY, ss = 0.f;
    for (int i = start + slot; i < end; i += 64) {
        float a = alphap[(size_t)i * 4 + hh] + aldh;
        a = a > 0.f ? a : 0.2f * a;                 // leaky_relu 0.2
        if (a > m) { ss = ss * __expf(m - a) + 1.f; m = a; }
        else ss += __expf(a - m);
    }
    rm[t] = m; rs[t] = ss;
    __syncthreads();
#pragma unroll
    for (int s2 = 128; s2 >= 4; s2 >>= 1) {
        if (t < s2) {
            float ma = rm[t], sa = rs[t];
            float mb = rm[t + s2], sb = rs[t + s2];
            float mm = fmaxf(ma, mb);
            float sv = 0.f;
            if (ma > -INFINITY) sv += sa * __expf(ma - mm);
            if (mb > -INFINITY) sv += sb * __expf(mb - mm);
            rm[t] = mm; rs[t] = sv;
        }
        __syncthreads();
    }
    if (t < 4) { mh[t] = rm[t]; inv[t] = 1.f / (rs[t] + 1e-16f); }
    __syncthreads();
    // phase 2: chunked weighted gather of xh[src] rows
    float acc0 = 0.f, acc1 = 0.f;
    int h0 = t >> 7;      // head of element j = t   (0/1)
    int h1 = h0 + 2;      // head of element j = t+256 (2/3)
    for (int cb = start; cb < end; cb += 128) {
        int cnt = min(128, end - cb);
        for (int z = t; z < cnt * 4; z += 256) {
            int hz = z & 3;
            float a = alphap[(size_t)cb * 4 + z] + ald[n * 4 + hz];
            a = a > 0.f ? a : 0.2f * a;
            wl[z] = __expf(a - mh[hz]) * inv[hz];
        }
        for (int z = t; z < cnt; z += 256) sl[z] = psrc[cb + z];
        __syncthreads();
        for (int i2 = 0; i2 < cnt; i2++) {
            const float* xr = xh + (size_t)sl[i2] * 512;
            acc0 += wl[i2 * 4 + h0] * xr[t];
            acc1 += wl[i2 * 4 + h1] * xr[t + 256];
        }
        __syncthreads();
    }
    // epilogue: mean heads + bias + relu + residual + LayerNorm
    wl[t] = acc0; wl[t + 256] = acc1;
    __syncthreads();
    float v = 0.f;
    if (t < 128) {
        float o = 0.25f * (wl[t] + wl[128 + t] + wl[256 + t] + wl[384 + t]) + bias[t];
        v = hio[(size_t)n * 128 + t] + fmaxf(o, 0.f);
        rm[t] = v; rs[t] = v * v;
    }
    __syncthreads();
#pragma unroll
    for (int s2 = 64; s2 >= 1; s2 >>= 1) {
        if (t < s2) { rm[t] += rm[t + s2]; rs[t] += rs[t + s2]; }
        __syncthreads();
    }
    if (t < 128) {
        float mean = rm[0] * (1.f / 128.f);
        float var = rs[0] * (1.f / 128.f) - mean * mean;
        float rinv = rsqrtf(var + 1e-5f);
        hio[(size_t)n * 128 + t] = (v - mean) * rinv * lnsc[t] + lnbi[t];
    }
}

// ---------------- output projection ----------------
__global__ __launch_bounds__(256) void k_out(
    const float* __restrict__ h, const float* __restrict__ ow,
    const float* __restrict__ ob, float* __restrict__ out) {
    __shared__ float4 hs4[8][32];
    int t = threadIdx.x;
    int n0 = blockIdx.x * 8;
    if (t < 256) {
        int i = t >> 5, kb = t & 31;
        hs4[i][kb] = *(const float4*)(h + (size_t)(n0 + i) * 128 + 4 * kb);
    }
    __syncthreads();
    float acc[8] = {0, 0, 0, 0, 0, 0, 0, 0};
    for (int kb = 0; kb < 32; kb++) {
        float w0 = ow[(4 * kb + 0) * 256 + t];
        float w1 = ow[(4 * kb + 1) * 256 + t];
        float w2 = ow[(4 * kb + 2) * 256 + t];
        float w3 = ow[(4 * kb + 3) * 256 + t];
#pragma unroll
        for (int i = 0; i < 8; i++) {
            float4 hv = hs4[i][kb];
            acc[i] += hv.x * w0 + hv.y * w1 + hv.z * w2 + hv.w * w3;
        }
    }
    float b = ob[t];
#pragma unroll
    for (int i = 0; i < 8; i++) out[(size_t)(n0 + i) * 256 + t] = acc[i] + b;
}

extern "C" void kernel_launch(void* const* d_in, const int* in_sizes, int n_in,
                              void* d_out, int out_size, void* d_ws, size_t ws_size,
                              hipStream_t stream) {
    const float* x    = (const float*)d_in[0];
    const int*   ei   = (const int*)d_in[1];
    const float* ea   = (const float*)d_in[2];
    const float* vnfc = (const float*)d_in[3];
    const float* nw   = (const float*)d_in[4];
    const float* nb   = (const float*)d_in[5];
    const float* eaw  = (const float*)d_in[6];
    const float* eab  = (const float*)d_in[7];
    const float* vw   = (const float*)d_in[8];
    const float* vb   = (const float*)d_in[9];
    const float* a1w  = (const float*)d_in[10];
    const float* a1b  = (const float*)d_in[11];
    const float* a2w  = (const float*)d_in[12];
    const float* a2b  = (const float*)d_in[13];
    const float* a3w  = (const float*)d_in[14];
    const float* a3b  = (const float*)d_in[15];
    const float* glw  = (const float*)d_in[16];
    const float* gas  = (const float*)d_in[17];
    const float* gad  = (const float*)d_in[18];
    const float* glew = (const float*)d_in[19];
    const float* gae  = (const float*)d_in[20];
    const float* gb   = (const float*)d_in[21];
    const float* lnsc = (const float*)d_in[22];
    const float* lnbi = (const float*)d_in[23];
    const float* ow   = (const float*)d_in[24];
    const float* ob   = (const float*)d_in[25];
    float* out = (float*)d_out;

    char* w = (char*)d_ws;
    size_t o = 0;
    auto allocf = [&](size_t cnt) { float* p = (float*)(w + o); o += ((cnt * 4 + 255) / 256) * 256; return p; };
    auto alloci = [&](size_t cnt) { int* p = (int*)(w + o); o += ((cnt * 4 + 255) / 256) * 256; return p; };
    float* h      = allocf((size_t)Nn * 128);
    float* xh     = allocf((size_t)Nn * 512);
    float* als    = allocf((size_t)Nn * 4);
    float* ald    = allocf((size_t)Nn * 4);
    float* ale    = allocf((size_t)Ee * 24);
    float* alphap = allocf((size_t)ET * 4);
    float* Bs     = allocf(3072);
    float* Bd     = allocf(3072);
    float* Be     = allocf(3072);
    float* M1     = allocf(512);
    float* d1     = allocf(128);
    float* wsum   = allocf(128);
    float* lale   = allocf(32);
    int* seg  = alloci(Nn + 1);
    int* hist = alloci(Nn);
    int* pos  = alloci(Nn);
    int* peid = alloci(ET);
    int* psrc = alloci(ET);

    hipMemsetAsync(hist, 0, Nn * sizeof(int), stream);
    hipMemsetAsync(wsum, 0, 128 * sizeof(float), stream);

    k_node_embed<<<(Nn * 128 + 255) / 256, 256, 0, stream>>>(x, nw, nb, h);
    k_small<<<1, 512, 0, stream>>>(vnfc, vw, vb, eab, a1w, a1b, eaw, M1, d1);
    k_bmat<<<(LL * 128 * 4 + 255) / 256, 256, 0, stream>>>(glw, gas, gad, glew, gae, Bs, Bd, Be);
    k_edge_mlp<<<4096, 64, 0, stream>>>(ea, M1, d1, a2w, a2b, a3w, a3b, eaw, eab, Be, ale, wsum);
    k_hist<<<(ET + 255) / 256, 256, 0, stream>>>(ei, hist);
    k_scan<<<1, 1024, 0, stream>>>(hist, seg, pos);
    k_scatter<<<(ET + 255) / 256, 256, 0, stream>>>(ei, pos, peid, psrc);
    k_loop_ale<<<1, 64, 0, stream>>>(wsum, Be, lale);
    for (int l = 0; l < LL; l++) {
        k_xh<<<Nn / 16, 256, 0, stream>>>(h, glw + (size_t)l * 65536, Bs + l * 512, Bd + l * 512,
                                          xh, als, ald);
        k_alpha<<<(ET + 255) / 256, 256, 0, stream>>>(peid, psrc, als, ale, lale, l, alphap);
        k_agg<<<Nn, 256, 0, stream>>>(alphap, psrc, seg, xh, ald,
                                      gb + l * 128, lnsc + l * 128, lnbi + l * 128, h);
    }
    k_out<<<Nn / 8, 256, 0, stream>>>(h, ow, ob, out);
}

// Round 2
// 928.031 us; speedup vs baseline: 1.2367x; 1.2367x over previous
//
#include <hip/hip_runtime.h>
#include <hip/hip_bf16.h>
#include <math.h>

#define Nn 10000
#define Ee 160000
#define ET 170000   // Ee + Nn (self loops)
#define LL 6

// ---------------- node embedding: h = x @ node_w + node_b ----------------
__global__ void k_node_embed(const float* __restrict__ x, const float* __restrict__ nw,
                             const float* __restrict__ nb, float* __restrict__ h) {
    int idx = blockIdx.x * 256 + threadIdx.x;
    if (idx >= Nn * 128) return;
    int n = idx >> 7, c = idx & 127;
    const float* xr = x + (size_t)n * 8;
    float acc = nb[c];
#pragma unroll
    for (int k = 0; k < 8; k++) acc += xr[k] * nw[k * 128 + c];
    h[idx] = acc;
}

// ---------------- small precompute: vnf_row, d1, M1 ----------------
__global__ void k_small(const float* __restrict__ vnfc, const float* __restrict__ vw,
                        const float* __restrict__ vb, const float* __restrict__ eab,
                        const float* __restrict__ a1w, const float* __restrict__ a1b,
                        const float* __restrict__ eaw, float* __restrict__ M1,
                        float* __restrict__ d1) {
    __shared__ float vr[128];
    int t = threadIdx.x;
    if (t < 128) {
        float a = vb[t];
#pragma unroll
        for (int k = 0; k < 6; k++) a += vnfc[k] * vw[k * 128 + t];
        vr[t] = a;
    }
    __syncthreads();
    if (t < 128) {
        float a = a1b[t];
        for (int k = 0; k < 128; k++) a += eab[k] * a1w[k * 128 + t];
        for (int k = 0; k < 128; k++) a += vr[k] * a1w[(128 + k) * 128 + t];
        d1[t] = a;
    }
    {
        int r = t >> 7, j = t & 127;   // t < 512 -> r in [0,4)
        float a = 0.f;
        for (int k = 0; k < 128; k++) a += eaw[r * 128 + k] * a1w[k * 128 + j];
        M1[r * 128 + j] = a;
    }
}

// ---------------- B matrices: Bs/Bd/Be [L][128][4] ----------------
__global__ void k_bmat(const float* __restrict__ glw, const float* __restrict__ gas,
                       const float* __restrict__ gad, const float* __restrict__ glew,
                       const float* __restrict__ gae, float* __restrict__ Bs,
                       float* __restrict__ Bd, float* __restrict__ Be) {
    int idx = blockIdx.x * 256 + threadIdx.x;
    if (idx >= LL * 128 * 4) return;
    int hh = idx & 3, k = (idx >> 2) & 127, l = idx >> 9;
    const float* lwp = glw  + (size_t)l * 65536 + k * 512 + hh * 128;
    const float* lep = glew + (size_t)l * 65536 + k * 512 + hh * 128;
    const float* sp = gas + l * 512 + hh * 128;
    const float* dp = gad + l * 512 + hh * 128;
    const float* ep = gae + l * 512 + hh * 128;
    float s1 = 0, s2 = 0, s3 = 0;
    for (int c = 0; c < 128; c++) {
        float lv = lwp[c];
        s1 += lv * sp[c];
        s2 += lv * dp[c];
        s3 += lep[c] * ep[c];
    }
    Bs[idx] = s1; Bd[idx] = s2; Be[idx] = s3;
}

// ---------------- PB[4][24], cB[24]: fold ea_proj through Be ----------------
__global__ void k_pb(const float* __restrict__ eaw, const float* __restrict__ eab,
                     const float* __restrict__ Be, float* __restrict__ PB,
                     float* __restrict__ cB) {
    int t = threadIdx.x;
    if (t >= 24) return;
    int l = t >> 2, hh = t & 3;
    const float* bp = Be + l * 512 + hh;
    float s0 = 0, s1 = 0, s2 = 0, s3 = 0, sc = 0;
    for (int k = 0; k < 128; k++) {
        float bv = bp[k * 4];
        s0 += eaw[0 * 128 + k] * bv;
        s1 += eaw[1 * 128 + k] * bv;
        s2 += eaw[2 * 128 + k] * bv;
        s3 += eaw[3 * 128 + k] * bv;
        sc += eab[k] * bv;
    }
    PB[0 * 24 + t] = s0; PB[1 * 24 + t] = s1;
    PB[2 * 24 + t] = s2; PB[3 * 24 + t] = s3;
    cB[t] = sc;
}

// ---------------- edge gate MLP, one thread per edge, no barriers ----------------
// a1 computed on the fly (never stored); weight reads are lane-uniform -> scalar loads.
__global__ __launch_bounds__(256) void k_edge(
    const float* __restrict__ ea, const float* __restrict__ M1, const float* __restrict__ d1,
    const float* __restrict__ a2w, const float* __restrict__ a2b,
    const float* __restrict__ a3w, const float* __restrict__ a3b,
    const float* __restrict__ PB, const float* __restrict__ cB,
    float* __restrict__ ale, float* __restrict__ gsum) {
    int e = blockIdx.x * 256 + threadIdx.x;   // grid sized exactly Ee
    float4 ev = *(const float4*)(ea + (size_t)e * 4);
    float acc[64];
#pragma unroll
    for (int j = 0; j < 64; j++) acc[j] = a2b[j];
    for (int k = 0; k < 128; k++) {
        float a1k = d1[k] + ev.x * M1[k] + ev.y * M1[128 + k]
                  + ev.z * M1[256 + k] + ev.w * M1[384 + k];
        a1k = fmaxf(a1k, 0.f);
        const float* w2r = a2w + k * 64;
#pragma unroll
        for (int j4 = 0; j4 < 16; j4++) {
            float4 wv = *(const float4*)(w2r + j4 * 4);
            acc[4 * j4 + 0] += a1k * wv.x;
            acc[4 * j4 + 1] += a1k * wv.y;
            acc[4 * j4 + 2] += a1k * wv.z;
            acc[4 * j4 + 3] += a1k * wv.w;
        }
    }
    float pr = 0.f;
#pragma unroll
    for (int j = 0; j < 64; j++) pr += fmaxf(acc[j], 0.f) * a3w[j];
    float g = 1.f / (1.f + __expf(-(pr + a3b[0])));
    // al_e for all 6 layers: g * (cB + e . PB)
#pragma unroll
    for (int i4 = 0; i4 < 6; i4++) {
        float4 c  = *(const float4*)(cB + i4 * 4);
        float4 p0 = *(const float4*)(PB + 0 * 24 + i4 * 4);
        float4 p1 = *(const float4*)(PB + 1 * 24 + i4 * 4);
        float4 p2 = *(const float4*)(PB + 2 * 24 + i4 * 4);
        float4 p3 = *(const float4*)(PB + 3 * 24 + i4 * 4);
        float4 o;
        o.x = g * (c.x + ev.x * p0.x + ev.y * p1.x + ev.z * p2.x + ev.w * p3.x);
        o.y = g * (c.y + ev.x * p0.y + ev.y * p1.y + ev.z * p2.y + ev.w * p3.y);
        o.z = g * (c.z + ev.x * p0.z + ev.y * p1.z + ev.z * p2.z + ev.w * p3.z);
        o.w = g * (c.w + ev.x * p0.w + ev.y * p1.w + ev.z * p2.w + ev.w * p3.w);
        *(float4*)(ale + (size_t)e * 24 + i4 * 4) = o;
    }
    // 5-scalar reduction for mean w_edge: G, S_r
    float v0 = g, v1 = g * ev.x, v2 = g * ev.y, v3 = g * ev.z, v4 = g * ev.w;
#pragma unroll
    for (int d = 32; d > 0; d >>= 1) {
        v0 += __shfl_down(v0, d); v1 += __shfl_down(v1, d); v2 += __shfl_down(v2, d);
        v3 += __shfl_down(v3, d); v4 += __shfl_down(v4, d);
    }
    if ((threadIdx.x & 63) == 0) {
        atomicAdd(&gsum[0], v0); atomicAdd(&gsum[1], v1); atomicAdd(&gsum[2], v2);
        atomicAdd(&gsum[3], v3); atomicAdd(&gsum[4], v4);
    }
}

// ---------------- loop-edge al_e from G,S sums ----------------
__global__ void k_lale(const float* __restrict__ gsum, const float* __restrict__ PB,
                       const float* __restrict__ cB, float* __restrict__ lale) {
    int t = threadIdx.x;
    if (t >= 24) return;
    float s = gsum[0] * cB[t] + gsum[1] * PB[t] + gsum[2] * PB[24 + t]
            + gsum[3] * PB[48 + t] + gsum[4] * PB[72 + t];
    lale[t] = s * (1.0f / Ee);
}

// ---------------- counting sort by dst: hist / scan / scatter ----------------
__global__ void k_hist(const int* __restrict__ ei, int* __restrict__ hist) {
    int i = blockIdx.x * 256 + threadIdx.x;
    if (i >= ET) return;
    int d = (i < Ee) ? ei[Ee + i] : (i - Ee);
    atomicAdd(&hist[d], 1);
}

__global__ __launch_bounds__(1024) void k_scan(const int* __restrict__ hist,
                                               int* __restrict__ seg, int* __restrict__ pos) {
    __shared__ int wsums[16];
    __shared__ int carry_s;
    int t = threadIdx.x;
    int lane = t & 63, wid = t >> 6;
    if (t == 0) { carry_s = 0; seg[0] = 0; }
    __syncthreads();
    for (int base = 0; base < Nn; base += 1024) {
        int idx = base + t;
        int v = (idx < Nn) ? hist[idx] : 0;
        int sc = v;
#pragma unroll
        for (int d = 1; d < 64; d <<= 1) {
            int up = __shfl_up(sc, d);
            if (lane >= d) sc += up;
        }
        if (lane == 63) wsums[wid] = sc;
        __syncthreads();
        if (wid == 0) {
            int wv = (lane < 16) ? wsums[lane] : 0;
            int wsc = wv;
#pragma unroll
            for (int d = 1; d < 16; d <<= 1) {
                int up = __shfl_up(wsc, d);
                if (lane >= d) wsc += up;
            }
            if (lane < 16) wsums[lane] = wsc - wv;   // exclusive wave offsets
        }
        __syncthreads();
        int carry = carry_s;
        int inc = sc + wsums[wid] + carry;
        if (idx < Nn) { seg[idx + 1] = inc; pos[idx] = inc - v; }
        __syncthreads();
        if (t == 1023) carry_s = inc;
        __syncthreads();
    }
}

__global__ void k_scatter(const int* __restrict__ ei, int* __restrict__ pos,
                          int* __restrict__ peid, int* __restrict__ psrc) {
    int i = blockIdx.x * 256 + threadIdx.x;
    if (i >= ET) return;
    int s, d;
    if (i < Ee) { s = ei[i]; d = ei[Ee + i]; } else { s = d = i - Ee; }
    int idx = atomicAdd(&pos[d], 1);
    peid[idx] = i;
    psrc[idx] = s;
}

// ---------------- per-layer: xh = h @ lw ; als/ald = h @ Bs/Bd ----------------
__global__ __launch_bounds__(256) void k_xh(
    const float* __restrict__ h, const float* __restrict__ lw,
    const float* __restrict__ Bs, const float* __restrict__ Bd,
    float* __restrict__ xh, float* __restrict__ als, float* __restrict__ ald) {
    __shared__ float4 hs4[16][32];
    int t = threadIdx.x;
    int n0 = blockIdx.x * 16;
    for (int z = t; z < 512; z += 256) {
        int i = z >> 5, kb = z & 31;
        hs4[i][kb] = *(const float4*)(h + (size_t)(n0 + i) * 128 + 4 * kb);
    }
    __syncthreads();
    int g = t >> 7;             // node group 0/1
    int c4 = (t & 127) * 4;     // col base (covers 512 cols)
    const float* lwc = lw + c4;
    float4 acc[8];
#pragma unroll
    for (int i = 0; i < 8; i++) acc[i] = make_float4(0.f, 0.f, 0.f, 0.f);
    for (int kb = 0; kb < 32; kb++) {
        float4 w0 = *(const float4*)(lwc + (size_t)(4 * kb + 0) * 512);
        float4 w1 = *(const float4*)(lwc + (size_t)(4 * kb + 1) * 512);
        float4 w2 = *(const float4*)(lwc + (size_t)(4 * kb + 2) * 512);
        float4 w3 = *(const float4*)(lwc + (size_t)(4 * kb + 3) * 512);
#pragma unroll
        for (int i = 0; i < 8; i++) {
            float4 hv = hs4[g * 8 + i][kb];
            acc[i].x += hv.x * w0.x + hv.y * w1.x + hv.z * w2.x + hv.w * w3.x;
            acc[i].y += hv.x * w0.y + hv.y * w1.y + hv.z * w2.y + hv.w * w3.y;
            acc[i].z += hv.x * w0.z + hv.y * w1.z + hv.z * w2.z + hv.w * w3.z;
            acc[i].w += hv.x * w0.w + hv.y * w1.w + hv.z * w2.w + hv.w * w3.w;
        }
    }
#pragma unroll
    for (int i = 0; i < 8; i++)
        *(float4*)(xh + (size_t)(n0 + g * 8 + i) * 512 + c4) = acc[i];
    if (t < 64) {
        int i = t >> 2, hh = t & 3;
        float s1 = 0, s2 = 0;
        for (int kb = 0; kb < 32; kb++) {
            float4 hv = hs4[i][kb];
            s1 += hv.x * Bs[(4 * kb + 0) * 4 + hh] + hv.y * Bs[(4 * kb + 1) * 4 + hh]
                + hv.z * Bs[(4 * kb + 2) * 4 + hh] + hv.w * Bs[(4 * kb + 3) * 4 + hh];
            s2 += hv.x * Bd[(4 * kb + 0) * 4 + hh] + hv.y * Bd[(4 * kb + 1) * 4 + hh]
                + hv.z * Bd[(4 * kb + 2) * 4 + hh] + hv.w * Bd[(4 * kb + 3) * 4 + hh];
        }
        als[(n0 + i) * 4 + hh] = s1;
        ald[(n0 + i) * 4 + hh] = s2;
    }
}

// ---------------- per-layer: alpha_partial (sorted order) = als[src] + al_e ----------------
__global__ void k_alpha(const int* __restrict__ peid, const int* __restrict__ psrc,
                        const float* __restrict__ als, const float* __restrict__ ale,
                        const float* __restrict__ lale, int l, float* __restrict__ alphap) {
    int i = blockIdx.x * 256 + threadIdx.x;
    if (i >= ET) return;
    int e = peid[i], s = psrc[i];
    float4 a = *(const float4*)(als + (size_t)s * 4);
    float4 b;
    if (e < Ee) b = *(const float4*)(ale + (size_t)e * 24 + l * 4);
    else        b = *(const float4*)(lale + l * 4);
    float4 o;
    o.x = a.x + b.x; o.y = a.y + b.y; o.z = a.z + b.z; o.w = a.w + b.w;
    *(float4*)(alphap + (size_t)i * 4) = o;
}

// ---------------- per-layer: segment softmax + gather-aggregate + LN ----------------
__global__ __launch_bounds__(256) void k_agg(
    const float* __restrict__ alphap, const int* __restrict__ psrc,
    const int* __restrict__ seg, const float* __restrict__ xh,
    const float* __restrict__ ald, const float* __restrict__ bias,
    const float* __restrict__ lnsc, const float* __restrict__ lnbi,
    float* __restrict__ hio) {
    __shared__ float rm[256], rs[256];
    __shared__ float wl[512];
    __shared__ float mh[4], inv[4];
    __shared__ int sl[128];
    int n = blockIdx.x, t = threadIdx.x;
    int start = seg[n], end = seg[n + 1];
    int hh = t & 3, slot = t >> 2;
    float aldh = ald[n * 4 + hh];
    float m = -INFINITY, ss = 0.f;
    for (int i = start + slot; i < end; i += 64) {
        float a = alphap[(size_t)i * 4 + hh] + aldh;
        a = a > 0.f ? a : 0.2f * a;                 // leaky_relu 0.2
        if (a > m) { ss = ss * __expf(m - a) + 1.f; m = a; }
        else ss += __expf(a - m);
    }
    rm[t] = m; rs[t] = ss;
    __syncthreads();
#pragma unroll
    for (int s2 = 128; s2 >= 4; s2 >>= 1) {
        if (t < s2) {
            float ma = rm[t], sa = rs[t];
            float mb = rm[t + s2], sb = rs[t + s2];
            float mm = fmaxf(ma, mb);
            float sv = 0.f;
            if (ma > -INFINITY) sv += sa * __expf(ma - mm);
            if (mb > -INFINITY) sv += sb * __expf(mb - mm);
            rm[t] = mm; rs[t] = sv;
        }
        __syncthreads();
    }
    if (t < 4) { mh[t] = rm[t]; inv[t] = 1.f / (rs[t] + 1e-16f); }
    __syncthreads();
    float acc0 = 0.f, acc1 = 0.f;
    int h0 = t >> 7;
    int h1 = h0 + 2;
    for (int cb = start; cb < end; cb += 128) {
        int cnt = min(128, end - cb);
        for (int z = t; z < cnt * 4; z += 256) {
            int hz = z & 3;
            float a = alphap[(size_t)cb * 4 + z] + ald[n * 4 + hz];
            a = a > 0.f ? a : 0.2f * a;
            wl[z] = __expf(a - mh[hz]) * inv[hz];
        }
        for (int z = t; z < cnt; z += 256) sl[z] = psrc[cb + z];
        __syncthreads();
        for (int i2 = 0; i2 < cnt; i2++) {
            const float* xr = xh + (size_t)sl[i2] * 512;
            acc0 += wl[i2 * 4 + h0] * xr[t];
            acc1 += wl[i2 * 4 + h1] * xr[t + 256];
        }
        __syncthreads();
    }
    wl[t] = acc0; wl[t + 256] = acc1;
    __syncthreads();
    float v = 0.f;
    if (t < 128) {
        float o = 0.25f * (wl[t] + wl[128 + t] + wl[256 + t] + wl[384 + t]) + bias[t];
        v = hio[(size_t)n * 128 + t] + fmaxf(o, 0.f);
        rm[t] = v; rs[t] = v * v;
    }
    __syncthreads();
#pragma unroll
    for (int s2 = 64; s2 >= 1; s2 >>= 1) {
        if (t < s2) { rm[t] += rm[t + s2]; rs[t] += rs[t + s2]; }
        __syncthreads();
    }
    if (t < 128) {
        float mean = rm[0] * (1.f / 128.f);
        float var = rs[0] * (1.f / 128.f) - mean * mean;
        float rinv = rsqrtf(var + 1e-5f);
        hio[(size_t)n * 128 + t] = (v - mean) * rinv * lnsc[t] + lnbi[t];
    }
}

// ---------------- output projection ----------------
__global__ __launch_bounds__(256) void k_out(
    const float* __restrict__ h, const float* __restrict__ ow,
    const float* __restrict__ ob, float* __restrict__ out) {
    __shared__ float4 hs4[8][32];
    int t = threadIdx.x;
    int n0 = blockIdx.x * 8;
    if (t < 256) {
        int i = t >> 5, kb = t & 31;
        hs4[i][kb] = *(const float4*)(h + (size_t)(n0 + i) * 128 + 4 * kb);
    }
    __syncthreads();
    float acc[8] = {0, 0, 0, 0, 0, 0, 0, 0};
    for (int kb = 0; kb < 32; kb++) {
        float w0 = ow[(4 * kb + 0) * 256 + t];
        float w1 = ow[(4 * kb + 1) * 256 + t];
        float w2 = ow[(4 * kb + 2) * 256 + t];
        float w3 = ow[(4 * kb + 3) * 256 + t];
#pragma unroll
        for (int i = 0; i < 8; i++) {
            float4 hv = hs4[i][kb];
            acc[i] += hv.x * w0 + hv.y * w1 + hv.z * w2 + hv.w * w3;
        }
    }
    float b = ob[t];
#pragma unroll
    for (int i = 0; i < 8; i++) out[(size_t)(n0 + i) * 256 + t] = acc[i] + b;
}

extern "C" void kernel_launch(void* const* d_in, const int* in_sizes, int n_in,
                              void* d_out, int out_size, void* d_ws, size_t ws_size,
                              hipStream_t stream) {
    const float* x    = (const float*)d_in[0];
    const int*   ei   = (const int*)d_in[1];
    const float* ea   = (const float*)d_in[2];
    const float* vnfc = (const float*)d_in[3];
    const float* nw   = (const float*)d_in[4];
    const float* nb   = (const float*)d_in[5];
    const float* eaw  = (const float*)d_in[6];
    const float* eab  = (const float*)d_in[7];
    const float* vw   = (const float*)d_in[8];
    const float* vb   = (const float*)d_in[9];
    const float* a1w  = (const float*)d_in[10];
    const float* a1b  = (const float*)d_in[11];
    const float* a2w  = (const float*)d_in[12];
    const float* a2b  = (const float*)d_in[13];
    const float* a3w  = (const float*)d_in[14];
    const float* a3b  = (const float*)d_in[15];
    const float* glw  = (const float*)d_in[16];
    const float* gas  = (const float*)d_in[17];
    const float* gad  = (const float*)d_in[18];
    const float* glew = (const float*)d_in[19];
    const float* gae  = (const float*)d_in[20];
    const float* gb   = (const float*)d_in[21];
    const float* lnsc = (const float*)d_in[22];
    const float* lnbi = (const float*)d_in[23];
    const float* ow   = (const float*)d_in[24];
    const float* ob   = (const float*)d_in[25];
    float* out = (float*)d_out;

    char* w = (char*)d_ws;
    size_t o = 0;
    auto allocf = [&](size_t cnt) { float* p = (float*)(w + o); o += ((cnt * 4 + 255) / 256) * 256; return p; };
    auto alloci = [&](size_t cnt) { int* p = (int*)(w + o); o += ((cnt * 4 + 255) / 256) * 256; return p; };
    float* h      = allocf((size_t)Nn * 128);
    float* xh     = allocf((size_t)Nn * 512);
    float* als    = allocf((size_t)Nn * 4);
    float* ald    = allocf((size_t)Nn * 4);
    float* ale    = allocf((size_t)Ee * 24);
    float* alphap = allocf((size_t)ET * 4);
    float* Bs     = allocf(3072);
    float* Bd     = allocf(3072);
    float* Be     = allocf(3072);
    float* M1     = allocf(512);
    float* d1     = allocf(128);
    float* PB     = allocf(96);
    float* cB     = allocf(24);
    float* gsum   = allocf(8);
    float* lale   = allocf(32);
    int* seg  = alloci(Nn + 1);
    int* hist = alloci(Nn);
    int* pos  = alloci(Nn);
    int* peid = alloci(ET);
    int* psrc = alloci(ET);

    hipMemsetAsync(hist, 0, Nn * sizeof(int), stream);
    hipMemsetAsync(gsum, 0, 8 * sizeof(float), stream);

    k_node_embed<<<(Nn * 128 + 255) / 256, 256, 0, stream>>>(x, nw, nb, h);
    k_small<<<1, 512, 0, stream>>>(vnfc, vw, vb, eab, a1w, a1b, eaw, M1, d1);
    k_bmat<<<(LL * 128 * 4 + 255) / 256, 256, 0, stream>>>(glw, gas, gad, glew, gae, Bs, Bd, Be);
    k_pb<<<1, 32, 0, stream>>>(eaw, eab, Be, PB, cB);
    k_edge<<<Ee / 256, 256, 0, stream>>>(ea, M1, d1, a2w, a2b, a3w, a3b, PB, cB, ale, gsum);
    k_hist<<<(ET + 255) / 256, 256, 0, stream>>>(ei, hist);
    k_scan<<<1, 1024, 0, stream>>>(hist, seg, pos);
    k_scatter<<<(ET + 255) / 256, 256, 0, stream>>>(ei, pos, peid, psrc);
    k_lale<<<1, 32, 0, stream>>>(gsum, PB, cB, lale);
    for (int l = 0; l < LL; l++) {
        k_xh<<<Nn / 16, 256, 0, stream>>>(h, glw + (size_t)l * 65536, Bs + l * 512, Bd + l * 512,
                                          xh, als, ald);
        k_alpha<<<(ET + 255) / 256, 256, 0, stream>>>(peid, psrc, als, ale, lale, l, alphap);
        k_agg<<<Nn, 256, 0, stream>>>(alphap, psrc, seg, xh, ald,
                                      gb + l * 128, lnsc + l * 128, lnbi + l * 128, h);
    }
    k_out<<<Nn / 8, 256, 0, stream>>>(h, ow, ob, out);
}

// Round 3
// 891.289 us; speedup vs baseline: 1.2877x; 1.0412x over previous
//
#include <hip/hip_runtime.h>
#include <hip/hip_bf16.h>
#include <math.h>

#define Nn 10000
#define Ee 160000
#define ET 170000   // Ee + Nn (self loops)
#define LL 6

// ---------------- node embedding: h = x @ node_w + node_b ----------------
__global__ void k_node_embed(const float* __restrict__ x, const float* __restrict__ nw,
                             const float* __restrict__ nb, float* __restrict__ h) {
    int idx = blockIdx.x * 256 + threadIdx.x;
    if (idx >= Nn * 128) return;
    int n = idx >> 7, c = idx & 127;
    const float* xr = x + (size_t)n * 8;
    float acc = nb[c];
#pragma unroll
    for (int k = 0; k < 8; k++) acc += xr[k] * nw[k * 128 + c];
    h[idx] = acc;
}

// ---------------- small precompute: E1[128][8] = {M1[0..3][k], d1[k], 0,0,0} ----------------
__global__ void k_small(const float* __restrict__ vnfc, const float* __restrict__ vw,
                        const float* __restrict__ vb, const float* __restrict__ eab,
                        const float* __restrict__ a1w, const float* __restrict__ a1b,
                        const float* __restrict__ eaw, float* __restrict__ E1) {
    __shared__ float vr[128];
    __shared__ float sM1[512];
    __shared__ float sd1[128];
    int t = threadIdx.x;   // 512
    if (t < 128) {
        float a = vb[t];
#pragma unroll
        for (int k = 0; k < 6; k++) a += vnfc[k] * vw[k * 128 + t];
        vr[t] = a;
    }
    __syncthreads();
    if (t < 128) {
        float a = a1b[t];
        for (int k = 0; k < 128; k++) a += eab[k] * a1w[k * 128 + t];
        for (int k = 0; k < 128; k++) a += vr[k] * a1w[(128 + k) * 128 + t];
        sd1[t] = a;
    }
    {
        int r = t >> 7, j = t & 127;
        float a = 0.f;
        for (int k = 0; k < 128; k++) a += eaw[r * 128 + k] * a1w[k * 128 + j];
        sM1[r * 128 + j] = a;
    }
    __syncthreads();
    if (t < 128) {
        E1[t * 8 + 0] = sM1[t];
        E1[t * 8 + 1] = sM1[128 + t];
        E1[t * 8 + 2] = sM1[256 + t];
        E1[t * 8 + 3] = sM1[384 + t];
        E1[t * 8 + 4] = sd1[t];
        E1[t * 8 + 5] = 0.f; E1[t * 8 + 6] = 0.f; E1[t * 8 + 7] = 0.f;
    }
}

// ---------------- B matrices: Bs/Bd/Be [L][128][4] ----------------
__global__ void k_bmat(const float* __restrict__ glw, const float* __restrict__ gas,
                       const float* __restrict__ gad, const float* __restrict__ glew,
                       const float* __restrict__ gae, float* __restrict__ Bs,
                       float* __restrict__ Bd, float* __restrict__ Be) {
    int idx = blockIdx.x * 256 + threadIdx.x;
    if (idx >= LL * 128 * 4) return;
    int hh = idx & 3, k = (idx >> 2) & 127, l = idx >> 9;
    const float* lwp = glw  + (size_t)l * 65536 + k * 512 + hh * 128;
    const float* lep = glew + (size_t)l * 65536 + k * 512 + hh * 128;
    const float* sp = gas + l * 512 + hh * 128;
    const float* dp = gad + l * 512 + hh * 128;
    const float* ep = gae + l * 512 + hh * 128;
    float s1 = 0, s2 = 0, s3 = 0;
    for (int c = 0; c < 128; c++) {
        float lv = lwp[c];
        s1 += lv * sp[c];
        s2 += lv * dp[c];
        s3 += lep[c] * ep[c];
    }
    Bs[idx] = s1; Bd[idx] = s2; Be[idx] = s3;
}

// ---------------- PB[4][24], cB[24]: fold ea_proj through Be ----------------
__global__ void k_pb(const float* __restrict__ eaw, const float* __restrict__ eab,
                     const float* __restrict__ Be, float* __restrict__ PB,
                     float* __restrict__ cB) {
    int t = threadIdx.x;
    if (t >= 24) return;
    int l = t >> 2, hh = t & 3;
    const float* bp = Be + l * 512 + hh;
    float s0 = 0, s1 = 0, s2 = 0, s3 = 0, sc = 0;
    for (int k = 0; k < 128; k++) {
        float bv = bp[k * 4];
        s0 += eaw[0 * 128 + k] * bv;
        s1 += eaw[1 * 128 + k] * bv;
        s2 += eaw[2 * 128 + k] * bv;
        s3 += eaw[3 * 128 + k] * bv;
        sc += eab[k] * bv;
    }
    PB[0 * 24 + t] = s0; PB[1 * 24 + t] = s1;
    PB[2 * 24 + t] = s2; PB[3 * 24 + t] = s3;
    cB[t] = sc;
}

// ---------------- edge gate MLP: 64 edges/block, 4 waves split the 64 j-columns ----------
__global__ __launch_bounds__(256) void k_edge(
    const float* __restrict__ ea, const float* __restrict__ E1,
    const float* __restrict__ a2w, const float* __restrict__ a2b,
    const float* __restrict__ a3w, const float* __restrict__ a3b,
    const float* __restrict__ PB, const float* __restrict__ cB,
    float* __restrict__ ale, float* __restrict__ gsum) {
    __shared__ float prs[4][64];
    __shared__ float gsh[64];
    int t = threadIdx.x;
    int lane = t & 63;
    int p = t >> 6;                                    // wave id = column pass
    int ps = __builtin_amdgcn_readfirstlane(p);        // force scalar -> s_load weights
    int e = blockIdx.x * 64 + lane;
    float4 ev = *(const float4*)(ea + (size_t)e * 4);
    float acc[16];
#pragma unroll
    for (int j = 0; j < 16; j++) acc[j] = a2b[ps * 16 + j];
    const float* w2base = a2w + ps * 16;
    for (int k = 0; k < 128; k++) {
        float4 m = *(const float4*)(E1 + k * 8);
        float dk = E1[k * 8 + 4];
        float a1k = fmaxf(dk + ev.x * m.x + ev.y * m.y + ev.z * m.z + ev.w * m.w, 0.f);
        const float* w2r = w2base + k * 64;
#pragma unroll
        for (int j4 = 0; j4 < 4; j4++) {
            float4 wv = *(const float4*)(w2r + j4 * 4);
            acc[4 * j4 + 0] += a1k * wv.x;
            acc[4 * j4 + 1] += a1k * wv.y;
            acc[4 * j4 + 2] += a1k * wv.z;
            acc[4 * j4 + 3] += a1k * wv.w;
        }
    }
    float pr = 0.f;
#pragma unroll
    for (int j = 0; j < 16; j++) pr += fmaxf(acc[j], 0.f) * a3w[ps * 16 + j];
    prs[p][lane] = pr;
    __syncthreads();
    if (p == 0) {
        float tot = prs[0][lane] + prs[1][lane] + prs[2][lane] + prs[3][lane] + a3b[0];
        float g = 1.f / (1.f + __expf(-tot));
        gsh[lane] = g;
        // 5-scalar reduction for mean w_edge
        float v0 = g, v1 = g * ev.x, v2 = g * ev.y, v3 = g * ev.z, v4 = g * ev.w;
#pragma unroll
        for (int d = 32; d > 0; d >>= 1) {
            v0 += __shfl_down(v0, d); v1 += __shfl_down(v1, d); v2 += __shfl_down(v2, d);
            v3 += __shfl_down(v3, d); v4 += __shfl_down(v4, d);
        }
        if (lane == 0) {
            atomicAdd(&gsum[0], v0); atomicAdd(&gsum[1], v1); atomicAdd(&gsum[2], v2);
            atomicAdd(&gsum[3], v3); atomicAdd(&gsum[4], v4);
        }
    }
    __syncthreads();
    float g = gsh[lane];
    // al_e for 6 layer-groups: wave p writes group p; waves 0,1 also write 4,5
#pragma unroll
    for (int rep = 0; rep < 2; rep++) {
        int i4 = (rep == 0) ? ps : (ps < 2 ? ps + 4 : -1);
        if (i4 >= 0) {
            float4 c  = *(const float4*)(cB + i4 * 4);
            float4 p0 = *(const float4*)(PB + 0 * 24 + i4 * 4);
            float4 p1 = *(const float4*)(PB + 1 * 24 + i4 * 4);
            float4 p2 = *(const float4*)(PB + 2 * 24 + i4 * 4);
            float4 p3 = *(const float4*)(PB + 3 * 24 + i4 * 4);
            float4 o;
            o.x = g * (c.x + ev.x * p0.x + ev.y * p1.x + ev.z * p2.x + ev.w * p3.x);
            o.y = g * (c.y + ev.x * p0.y + ev.y * p1.y + ev.z * p2.y + ev.w * p3.y);
            o.z = g * (c.z + ev.x * p0.z + ev.y * p1.z + ev.z * p2.z + ev.w * p3.z);
            o.w = g * (c.w + ev.x * p0.w + ev.y * p1.w + ev.z * p2.w + ev.w * p3.w);
            *(float4*)(ale + (size_t)e * 24 + i4 * 4) = o;
        }
    }
}

// ---------------- loop-edge al_e from G,S sums ----------------
__global__ void k_lale(const float* __restrict__ gsum, const float* __restrict__ PB,
                       const float* __restrict__ cB, float* __restrict__ lale) {
    int t = threadIdx.x;
    if (t >= 24) return;
    float s = gsum[0] * cB[t] + gsum[1] * PB[t] + gsum[2] * PB[24 + t]
            + gsum[3] * PB[48 + t] + gsum[4] * PB[72 + t];
    lale[t] = s * (1.0f / Ee);
}

// ---------------- counting sort by dst: hist / scan / scatter ----------------
__global__ void k_hist(const int* __restrict__ ei, int* __restrict__ hist) {
    int i = blockIdx.x * 256 + threadIdx.x;
    if (i >= ET) return;
    int d = (i < Ee) ? ei[Ee + i] : (i - Ee);
    atomicAdd(&hist[d], 1);
}

__global__ __launch_bounds__(1024) void k_scan(const int* __restrict__ hist,
                                               int* __restrict__ seg, int* __restrict__ pos) {
    __shared__ int wsums[16];
    __shared__ int carry_s;
    int t = threadIdx.x;
    int lane = t & 63, wid = t >> 6;
    if (t == 0) { carry_s = 0; seg[0] = 0; }
    __syncthreads();
    for (int base = 0; base < Nn; base += 1024) {
        int idx = base + t;
        int v = (idx < Nn) ? hist[idx] : 0;
        int sc = v;
#pragma unroll
        for (int d = 1; d < 64; d <<= 1) {
            int up = __shfl_up(sc, d);
            if (lane >= d) sc += up;
        }
        if (lane == 63) wsums[wid] = sc;
        __syncthreads();
        if (wid == 0) {
            int wv = (lane < 16) ? wsums[lane] : 0;
            int wsc = wv;
#pragma unroll
            for (int d = 1; d < 16; d <<= 1) {
                int up = __shfl_up(wsc, d);
                if (lane >= d) wsc += up;
            }
            if (lane < 16) wsums[lane] = wsc - wv;
        }
        __syncthreads();
        int carry = carry_s;
        int inc = sc + wsums[wid] + carry;
        if (idx < Nn) { seg[idx + 1] = inc; pos[idx] = inc - v; }
        __syncthreads();
        if (t == 1023) carry_s = inc;
        __syncthreads();
    }
}

__global__ void k_scatter(const int* __restrict__ ei, int* __restrict__ pos,
                          int* __restrict__ peid, int* __restrict__ psrc,
                          int* __restrict__ pdst) {
    int i = blockIdx.x * 256 + threadIdx.x;
    if (i >= ET) return;
    int s, d;
    if (i < Ee) { s = ei[i]; d = ei[Ee + i]; } else { s = d = i - Ee; }
    int idx = atomicAdd(&pos[d], 1);
    peid[idx] = i;
    psrc[idx] = s;
    pdst[idx] = d;
}

// ---------------- per-layer: xh = h @ lw ; als/ald = h @ Bs/Bd ----------------
__global__ __launch_bounds__(256) void k_xh(
    const float* __restrict__ h, const float* __restrict__ lw,
    const float* __restrict__ Bs, const float* __restrict__ Bd,
    float* __restrict__ xh, float* __restrict__ als, float* __restrict__ ald) {
    __shared__ float4 hs4[16][32];
    int t = threadIdx.x;
    int n0 = blockIdx.x * 16;
    for (int z = t; z < 512; z += 256) {
        int i = z >> 5, kb = z & 31;
        hs4[i][kb] = *(const float4*)(h + (size_t)(n0 + i) * 128 + 4 * kb);
    }
    __syncthreads();
    int g = t >> 7;
    int c4 = (t & 127) * 4;
    const float* lwc = lw + c4;
    float4 acc[8];
#pragma unroll
    for (int i = 0; i < 8; i++) acc[i] = make_float4(0.f, 0.f, 0.f, 0.f);
    for (int kb = 0; kb < 32; kb++) {
        float4 w0 = *(const float4*)(lwc + (size_t)(4 * kb + 0) * 512);
        float4 w1 = *(const float4*)(lwc + (size_t)(4 * kb + 1) * 512);
        float4 w2 = *(const float4*)(lwc + (size_t)(4 * kb + 2) * 512);
        float4 w3 = *(const float4*)(lwc + (size_t)(4 * kb + 3) * 512);
#pragma unroll
        for (int i = 0; i < 8; i++) {
            float4 hv = hs4[g * 8 + i][kb];
            acc[i].x += hv.x * w0.x + hv.y * w1.x + hv.z * w2.x + hv.w * w3.x;
            acc[i].y += hv.x * w0.y + hv.y * w1.y + hv.z * w2.y + hv.w * w3.y;
            acc[i].z += hv.x * w0.z + hv.y * w1.z + hv.z * w2.z + hv.w * w3.z;
            acc[i].w += hv.x * w0.w + hv.y * w1.w + hv.z * w2.w + hv.w * w3.w;
        }
    }
#pragma unroll
    for (int i = 0; i < 8; i++)
        *(float4*)(xh + (size_t)(n0 + g * 8 + i) * 512 + c4) = acc[i];
    if (t < 64) {
        int i = t >> 2, hh = t & 3;
        float s1 = 0, s2 = 0;
        for (int kb = 0; kb < 32; kb++) {
            float4 hv = hs4[i][kb];
            s1 += hv.x * Bs[(4 * kb + 0) * 4 + hh] + hv.y * Bs[(4 * kb + 1) * 4 + hh]
                + hv.z * Bs[(4 * kb + 2) * 4 + hh] + hv.w * Bs[(4 * kb + 3) * 4 + hh];
            s2 += hv.x * Bd[(4 * kb + 0) * 4 + hh] + hv.y * Bd[(4 * kb + 1) * 4 + hh]
                + hv.z * Bd[(4 * kb + 2) * 4 + hh] + hv.w * Bd[(4 * kb + 3) * 4 + hh];
        }
        als[(n0 + i) * 4 + hh] = s1;
        ald[(n0 + i) * 4 + hh] = s2;
    }
}

// ---------------- per-layer: finished logits = leaky(als[src]+ald[dst]+al_e) ----------------
__global__ void k_alpha(const int* __restrict__ peid, const int* __restrict__ psrc,
                        const int* __restrict__ pdst, const float* __restrict__ als,
                        const float* __restrict__ ald, const float* __restrict__ ale,
                        const float* __restrict__ lale, int l, float* __restrict__ alphap) {
    int i = blockIdx.x * 256 + threadIdx.x;
    if (i >= ET) return;
    int e = peid[i], s = psrc[i], d = pdst[i];
    float4 a = *(const float4*)(als + (size_t)s * 4);
    float4 ad = *(const float4*)(ald + (size_t)d * 4);
    float4 b;
    if (e < Ee) b = *(const float4*)(ale + (size_t)e * 24 + l * 4);
    else        b = *(const float4*)(lale + l * 4);
    float4 o;
    o.x = a.x + ad.x + b.x; o.y = a.y + ad.y + b.y;
    o.z = a.z + ad.z + b.z; o.w = a.w + ad.w + b.w;
    o.x = o.x > 0.f ? o.x : 0.2f * o.x;
    o.y = o.y > 0.f ? o.y : 0.2f * o.y;
    o.z = o.z > 0.f ? o.z : 0.2f * o.z;
    o.w = o.w > 0.f ? o.w : 0.2f * o.w;
    *(float4*)(alphap + (size_t)i * 4) = o;
}

// ---------------- per-layer: segment softmax + gather-aggregate + LN ----------------
__global__ __launch_bounds__(256) void k_agg(
    const float* __restrict__ alphap, const int* __restrict__ psrc,
    const int* __restrict__ seg, const float* __restrict__ xh,
    const float* __restrict__ bias, const float* __restrict__ lnsc,
    const float* __restrict__ lnbi, float* __restrict__ hio) {
    __shared__ float rm[256], rs[256];
    __shared__ float wl[512];
    __shared__ float mh[4], inv[4];
    __shared__ int sl[128];
    int n = blockIdx.x, t = threadIdx.x;
    int start = seg[n], end = seg[n + 1];
    int hh = t & 3, slot = t >> 2;
    float m = -INFINITY, ss = 0.f;
    for (int i = start + slot; i < end; i += 64) {
        float a = alphap[(size_t)i * 4 + hh];
        if (a > m) { ss = ss * __expf(m - a) + 1.f; m = a; }
        else ss += __expf(a - m);
    }
    rm[t] = m; rs[t] = ss;
    __syncthreads();
#pragma unroll
    for (int s2 = 128; s2 >= 4; s2 >>= 1) {
        if (t < s2) {
            float ma = rm[t], sa = rs[t];
            float mb = rm[t + s2], sb = rs[t + s2];
            float mm = fmaxf(ma, mb);
            float sv = 0.f;
            if (ma > -INFINITY) sv += sa * __expf(ma - mm);
            if (mb > -INFINITY) sv += sb * __expf(mb - mm);
            rm[t] = mm; rs[t] = sv;
        }
        __syncthreads();
    }
    if (t < 4) { mh[t] = rm[t]; inv[t] = 1.f / (rs[t] + 1e-16f); }
    __syncthreads();
    float acc0 = 0.f, acc1 = 0.f;
    int h0 = t >> 7;
    int h1 = h0 + 2;
    for (int cb = start; cb < end; cb += 128) {
        int cnt = min(128, end - cb);
        for (int z = t; z < cnt * 4; z += 256) {
            int hz = z & 3;
            float a = alphap[(size_t)cb * 4 + z];
            wl[z] = __expf(a - mh[hz]) * inv[hz];
        }
        for (int z = t; z < cnt; z += 256) sl[z] = psrc[cb + z];
        __syncthreads();
        for (int i2 = 0; i2 < cnt; i2++) {
            const float* xr = xh + (size_t)sl[i2] * 512;
            acc0 += wl[i2 * 4 + h0] * xr[t];
            acc1 += wl[i2 * 4 + h1] * xr[t + 256];
        }
        __syncthreads();
    }
    wl[t] = acc0; wl[t + 256] = acc1;
    __syncthreads();
    float v = 0.f;
    if (t < 128) {
        float o = 0.25f * (wl[t] + wl[128 + t] + wl[256 + t] + wl[384 + t]) + bias[t];
        v = hio[(size_t)n * 128 + t] + fmaxf(o, 0.f);
        rm[t] = v; rs[t] = v * v;
    }
    __syncthreads();
#pragma unroll
    for (int s2 = 64; s2 >= 1; s2 >>= 1) {
        if (t < s2) { rm[t] += rm[t + s2]; rs[t] += rs[t + s2]; }
        __syncthreads();
    }
    if (t < 128) {
        float mean = rm[0] * (1.f / 128.f);
        float var = rs[0] * (1.f / 128.f) - mean * mean;
        float rinv = rsqrtf(var + 1e-5f);
        hio[(size_t)n * 128 + t] = (v - mean) * rinv * lnsc[t] + lnbi[t];
    }
}

// ---------------- output projection ----------------
__global__ __launch_bounds__(256) void k_out(
    const float* __restrict__ h, const float* __restrict__ ow,
    const float* __restrict__ ob, float* __restrict__ out) {
    __shared__ float4 hs4[8][32];
    int t = threadIdx.x;
    int n0 = blockIdx.x * 8;
    if (t < 256) {
        int i = t >> 5, kb = t & 31;
        hs4[i][kb] = *(const float4*)(h + (size_t)(n0 + i) * 128 + 4 * kb);
    }
    __syncthreads();
    float acc[8] = {0, 0, 0, 0, 0, 0, 0, 0};
    for (int kb = 0; kb < 32; kb++) {
        float w0 = ow[(4 * kb + 0) * 256 + t];
        float w1 = ow[(4 * kb + 1) * 256 + t];
        float w2 = ow[(4 * kb + 2) * 256 + t];
        float w3 = ow[(4 * kb + 3) * 256 + t];
#pragma unroll
        for (int i = 0; i < 8; i++) {
            float4 hv = hs4[i][kb];
            acc[i] += hv.x * w0 + hv.y * w1 + hv.z * w2 + hv.w * w3;
        }
    }
    float b = ob[t];
#pragma unroll
    for (int i = 0; i < 8; i++) out[(size_t)(n0 + i) * 256 + t] = acc[i] + b;
}

extern "C" void kernel_launch(void* const* d_in, const int* in_sizes, int n_in,
                              void* d_out, int out_size, void* d_ws, size_t ws_size,
                              hipStream_t stream) {
    const float* x    = (const float*)d_in[0];
    const int*   ei   = (const int*)d_in[1];
    const float* ea   = (const float*)d_in[2];
    const float* vnfc = (const float*)d_in[3];
    const float* nw   = (const float*)d_in[4];
    const float* nb   = (const float*)d_in[5];
    const float* eaw  = (const float*)d_in[6];
    const float* eab  = (const float*)d_in[7];
    const float* vw   = (const float*)d_in[8];
    const float* vb   = (const float*)d_in[9];
    const float* a1w  = (const float*)d_in[10];
    const float* a1b  = (const float*)d_in[11];
    const float* a2w  = (const float*)d_in[12];
    const float* a2b  = (const float*)d_in[13];
    const float* a3w  = (const float*)d_in[14];
    const float* a3b  = (const float*)d_in[15];
    const float* glw  = (const float*)d_in[16];
    const float* gas  = (const float*)d_in[17];
    const float* gad  = (const float*)d_in[18];
    const float* glew = (const float*)d_in[19];
    const float* gae  = (const float*)d_in[20];
    const float* gb   = (const float*)d_in[21];
    const float* lnsc = (const float*)d_in[22];
    const float* lnbi = (const float*)d_in[23];
    const float* ow   = (const float*)d_in[24];
    const float* ob   = (const float*)d_in[25];
    float* out = (float*)d_out;

    char* w = (char*)d_ws;
    size_t o = 0;
    auto allocf = [&](size_t cnt) { float* p = (float*)(w + o); o += ((cnt * 4 + 255) / 256) * 256; return p; };
    auto alloci = [&](size_t cnt) { int* p = (int*)(w + o); o += ((cnt * 4 + 255) / 256) * 256; return p; };
    float* h      = allocf((size_t)Nn * 128);
    float* xh     = allocf((size_t)Nn * 512);
    float* als    = allocf((size_t)Nn * 4);
    float* ald    = allocf((size_t)Nn * 4);
    float* ale    = allocf((size_t)Ee * 24);
    float* alphap = allocf((size_t)ET * 4);
    float* Bs     = allocf(3072);
    float* Bd     = allocf(3072);
    float* Be     = allocf(3072);
    float* E1     = allocf(1024);
    float* PB     = allocf(96);
    float* cB     = allocf(24);
    float* gsum   = allocf(8);
    float* lale   = allocf(32);
    int* seg  = alloci(Nn + 1);
    int* hist = alloci(Nn);
    int* pos  = alloci(Nn);
    int* peid = alloci(ET);
    int* psrc = alloci(ET);
    int* pdst = alloci(ET);

    hipMemsetAsync(hist, 0, Nn * sizeof(int), stream);
    hipMemsetAsync(gsum, 0, 8 * sizeof(float), stream);

    k_node_embed<<<(Nn * 128 + 255) / 256, 256, 0, stream>>>(x, nw, nb, h);
    k_small<<<1, 512, 0, stream>>>(vnfc, vw, vb, eab, a1w, a1b, eaw, E1);
    k_bmat<<<(LL * 128 * 4 + 255) / 256, 256, 0, stream>>>(glw, gas, gad, glew, gae, Bs, Bd, Be);
    k_pb<<<1, 32, 0, stream>>>(eaw, eab, Be, PB, cB);
    k_edge<<<Ee / 64, 256, 0, stream>>>(ea, E1, a2w, a2b, a3w, a3b, PB, cB, ale, gsum);
    k_hist<<<(ET + 255) / 256, 256, 0, stream>>>(ei, hist);
    k_scan<<<1, 1024, 0, stream>>>(hist, seg, pos);
    k_scatter<<<(ET + 255) / 256, 256, 0, stream>>>(ei, pos, peid, psrc, pdst);
    k_lale<<<1, 32, 0, stream>>>(gsum, PB, cB, lale);
    for (int l = 0; l < LL; l++) {
        k_xh<<<Nn / 16, 256, 0, stream>>>(h, glw + (size_t)l * 65536, Bs + l * 512, Bd + l * 512,
                                          xh, als, ald);
        k_alpha<<<(ET + 255) / 256, 256, 0, stream>>>(peid, psrc, pdst, als, ald, ale, lale, l, alphap);
        k_agg<<<Nn, 256, 0, stream>>>(alphap, psrc, seg, xh,
                                      gb + l * 128, lnsc + l * 128, lnbi + l * 128, h);
    }
    k_out<<<Nn / 8, 256, 0, stream>>>(h, ow, ob, out);
}

// Round 4
// 874.632 us; speedup vs baseline: 1.3122x; 1.0190x over previous
//
#include <hip/hip_runtime.h>
#include <hip/hip_bf16.h>
#include <math.h>

#define Nn 10000
#define Ee 160000
#define ET 170000   // Ee + Nn (self loops)
#define LL 6

// ---------------- node embedding: h = x @ node_w + node_b ----------------
__global__ void k_node_embed(const float* __restrict__ x, const float* __restrict__ nw,
                             const float* __restrict__ nb, float* __restrict__ h) {
    int idx = blockIdx.x * 256 + threadIdx.x;
    if (idx >= Nn * 128) return;
    int n = idx >> 7, c = idx & 127;
    const float* xr = x + (size_t)n * 8;
    float acc = nb[c];
#pragma unroll
    for (int k = 0; k < 8; k++) acc += xr[k] * nw[k * 128 + c];
    h[idx] = acc;
}

// ---------------- small precompute: E1[128][8] = {M1[0..3][k], d1[k], 0,0,0} ----------------
__global__ void k_small(const float* __restrict__ vnfc, const float* __restrict__ vw,
                        const float* __restrict__ vb, const float* __restrict__ eab,
                        const float* __restrict__ a1w, const float* __restrict__ a1b,
                        const float* __restrict__ eaw, float* __restrict__ E1) {
    __shared__ float vr[128];
    __shared__ float sM1[512];
    __shared__ float sd1[128];
    int t = threadIdx.x;   // 512
    if (t < 128) {
        float a = vb[t];
#pragma unroll
        for (int k = 0; k < 6; k++) a += vnfc[k] * vw[k * 128 + t];
        vr[t] = a;
    }
    __syncthreads();
    if (t < 128) {
        float a = a1b[t];
        for (int k = 0; k < 128; k++) a += eab[k] * a1w[k * 128 + t];
        for (int k = 0; k < 128; k++) a += vr[k] * a1w[(128 + k) * 128 + t];
        sd1[t] = a;
    }
    {
        int r = t >> 7, j = t & 127;
        float a = 0.f;
        for (int k = 0; k < 128; k++) a += eaw[r * 128 + k] * a1w[k * 128 + j];
        sM1[r * 128 + j] = a;
    }
    __syncthreads();
    if (t < 128) {
        E1[t * 8 + 0] = sM1[t];
        E1[t * 8 + 1] = sM1[128 + t];
        E1[t * 8 + 2] = sM1[256 + t];
        E1[t * 8 + 3] = sM1[384 + t];
        E1[t * 8 + 4] = sd1[t];
        E1[t * 8 + 5] = 0.f; E1[t * 8 + 6] = 0.f; E1[t * 8 + 7] = 0.f;
    }
}

// ---------------- B matrices: Bs/Bd/Be [L][128][4] ----------------
__global__ void k_bmat(const float* __restrict__ glw, const float* __restrict__ gas,
                       const float* __restrict__ gad, const float* __restrict__ glew,
                       const float* __restrict__ gae, float* __restrict__ Bs,
                       float* __restrict__ Bd, float* __restrict__ Be) {
    int idx = blockIdx.x * 256 + threadIdx.x;
    if (idx >= LL * 128 * 4) return;
    int hh = idx & 3, k = (idx >> 2) & 127, l = idx >> 9;
    const float* lwp = glw  + (size_t)l * 65536 + k * 512 + hh * 128;
    const float* lep = glew + (size_t)l * 65536 + k * 512 + hh * 128;
    const float* sp = gas + l * 512 + hh * 128;
    const float* dp = gad + l * 512 + hh * 128;
    const float* ep = gae + l * 512 + hh * 128;
    float s1 = 0, s2 = 0, s3 = 0;
    for (int c = 0; c < 128; c++) {
        float lv = lwp[c];
        s1 += lv * sp[c];
        s2 += lv * dp[c];
        s3 += lep[c] * ep[c];
    }
    Bs[idx] = s1; Bd[idx] = s2; Be[idx] = s3;
}

// ---------------- PB[4][24], cB[24]: fold ea_proj through Be ----------------
__global__ void k_pb(const float* __restrict__ eaw, const float* __restrict__ eab,
                     const float* __restrict__ Be, float* __restrict__ PB,
                     float* __restrict__ cB) {
    int t = threadIdx.x;
    if (t >= 24) return;
    int l = t >> 2, hh = t & 3;
    const float* bp = Be + l * 512 + hh;
    float s0 = 0, s1 = 0, s2 = 0, s3 = 0, sc = 0;
    for (int k = 0; k < 128; k++) {
        float bv = bp[k * 4];
        s0 += eaw[0 * 128 + k] * bv;
        s1 += eaw[1 * 128 + k] * bv;
        s2 += eaw[2 * 128 + k] * bv;
        s3 += eaw[3 * 128 + k] * bv;
        sc += eab[k] * bv;
    }
    PB[0 * 24 + t] = s0; PB[1 * 24 + t] = s1;
    PB[2 * 24 + t] = s2; PB[3 * 24 + t] = s3;
    cB[t] = sc;
}

// ---- edge gate MLP: 128 edges/block, 2 edges/lane, 4 waves split the 64 j-columns ----
__global__ __launch_bounds__(256) void k_edge(
    const float* __restrict__ ea, const float* __restrict__ E1,
    const float* __restrict__ a2w, const float* __restrict__ a2b,
    const float* __restrict__ a3w, const float* __restrict__ a3b,
    const float* __restrict__ PB, const float* __restrict__ cB,
    float* __restrict__ ale, float* __restrict__ gsum) {
    __shared__ float prs[4][128];
    __shared__ float gsh[128];
    int t = threadIdx.x;
    int lane = t & 63;
    int p = t >> 6;
    int ps = __builtin_amdgcn_readfirstlane(p);        // scalar -> s_load weights
    int e0 = blockIdx.x * 128 + lane;
    int e1 = e0 + 64;
    float4 ev0 = *(const float4*)(ea + (size_t)e0 * 4);
    float4 ev1 = *(const float4*)(ea + (size_t)e1 * 4);
    float acc0[16], acc1[16];
#pragma unroll
    for (int j = 0; j < 16; j++) { float b = a2b[ps * 16 + j]; acc0[j] = b; acc1[j] = b; }
    const float* w2base = a2w + ps * 16;
#pragma unroll 2
    for (int k = 0; k < 128; k++) {
        float4 m = *(const float4*)(E1 + k * 8);
        float dk = E1[k * 8 + 4];
        float x0 = fmaxf(dk + ev0.x * m.x + ev0.y * m.y + ev0.z * m.z + ev0.w * m.w, 0.f);
        float x1 = fmaxf(dk + ev1.x * m.x + ev1.y * m.y + ev1.z * m.z + ev1.w * m.w, 0.f);
        const float* w2r = w2base + k * 64;
#pragma unroll
        for (int j4 = 0; j4 < 4; j4++) {
            float4 wv = *(const float4*)(w2r + j4 * 4);
            acc0[4 * j4 + 0] += x0 * wv.x; acc1[4 * j4 + 0] += x1 * wv.x;
            acc0[4 * j4 + 1] += x0 * wv.y; acc1[4 * j4 + 1] += x1 * wv.y;
            acc0[4 * j4 + 2] += x0 * wv.z; acc1[4 * j4 + 2] += x1 * wv.z;
            acc0[4 * j4 + 3] += x0 * wv.w; acc1[4 * j4 + 3] += x1 * wv.w;
        }
    }
    float pr0 = 0.f, pr1 = 0.f;
#pragma unroll
    for (int j = 0; j < 16; j++) {
        float w3 = a3w[ps * 16 + j];
        pr0 += fmaxf(acc0[j], 0.f) * w3;
        pr1 += fmaxf(acc1[j], 0.f) * w3;
    }
    prs[p][lane] = pr0; prs[p][64 + lane] = pr1;
    __syncthreads();
    if (p == 0) {
        float v0 = 0.f, v1 = 0.f, v2 = 0.f, v3 = 0.f, v4 = 0.f;
#pragma unroll
        for (int rep = 0; rep < 2; rep++) {
            int le = rep * 64 + lane;
            float tot = prs[0][le] + prs[1][le] + prs[2][le] + prs[3][le] + a3b[0];
            float g = 1.f / (1.f + __expf(-tot));
            gsh[le] = g;
            float4 evv = rep == 0 ? ev0 : ev1;
            v0 += g; v1 += g * evv.x; v2 += g * evv.y; v3 += g * evv.z; v4 += g * evv.w;
        }
#pragma unroll
        for (int d = 32; d > 0; d >>= 1) {
            v0 += __shfl_down(v0, d); v1 += __shfl_down(v1, d); v2 += __shfl_down(v2, d);
            v3 += __shfl_down(v3, d); v4 += __shfl_down(v4, d);
        }
        if (lane == 0) {
            atomicAdd(&gsum[0], v0); atomicAdd(&gsum[1], v1); atomicAdd(&gsum[2], v2);
            atomicAdd(&gsum[3], v3); atomicAdd(&gsum[4], v4);
        }
    }
    __syncthreads();
    float g0 = gsh[lane], g1 = gsh[64 + lane];
#pragma unroll
    for (int rep = 0; rep < 2; rep++) {
        int i4 = (rep == 0) ? ps : (ps < 2 ? ps + 4 : -1);
        if (i4 >= 0) {
            float4 c  = *(const float4*)(cB + i4 * 4);
            float4 p0 = *(const float4*)(PB + 0 * 24 + i4 * 4);
            float4 p1 = *(const float4*)(PB + 1 * 24 + i4 * 4);
            float4 p2 = *(const float4*)(PB + 2 * 24 + i4 * 4);
            float4 p3 = *(const float4*)(PB + 3 * 24 + i4 * 4);
            float4 o;
            o.x = g0 * (c.x + ev0.x * p0.x + ev0.y * p1.x + ev0.z * p2.x + ev0.w * p3.x);
            o.y = g0 * (c.y + ev0.x * p0.y + ev0.y * p1.y + ev0.z * p2.y + ev0.w * p3.y);
            o.z = g0 * (c.z + ev0.x * p0.z + ev0.y * p1.z + ev0.z * p2.z + ev0.w * p3.z);
            o.w = g0 * (c.w + ev0.x * p0.w + ev0.y * p1.w + ev0.z * p2.w + ev0.w * p3.w);
            *(float4*)(ale + (size_t)e0 * 24 + i4 * 4) = o;
            float4 q;
            q.x = g1 * (c.x + ev1.x * p0.x + ev1.y * p1.x + ev1.z * p2.x + ev1.w * p3.x);
            q.y = g1 * (c.y + ev1.x * p0.y + ev1.y * p1.y + ev1.z * p2.y + ev1.w * p3.y);
            q.z = g1 * (c.z + ev1.x * p0.z + ev1.y * p1.z + ev1.z * p2.z + ev1.w * p3.z);
            q.w = g1 * (c.w + ev1.x * p0.w + ev1.y * p1.w + ev1.z * p2.w + ev1.w * p3.w);
            *(float4*)(ale + (size_t)e1 * 24 + i4 * 4) = q;
        }
    }
}

// ---------------- loop-edge al_e from G,S sums ----------------
__global__ void k_lale(const float* __restrict__ gsum, const float* __restrict__ PB,
                       const float* __restrict__ cB, float* __restrict__ lale) {
    int t = threadIdx.x;
    if (t >= 24) return;
    float s = gsum[0] * cB[t] + gsum[1] * PB[t] + gsum[2] * PB[24 + t]
            + gsum[3] * PB[48 + t] + gsum[4] * PB[72 + t];
    lale[t] = s * (1.0f / Ee);
}

// ---------------- counting sort by dst: hist / scan / scatter ----------------
__global__ void k_hist(const int* __restrict__ ei, int* __restrict__ hist) {
    int i = blockIdx.x * 256 + threadIdx.x;
    if (i >= ET) return;
    int d = (i < Ee) ? ei[Ee + i] : (i - Ee);
    atomicAdd(&hist[d], 1);
}

__global__ __launch_bounds__(1024) void k_scan(const int* __restrict__ hist,
                                               int* __restrict__ seg, int* __restrict__ pos) {
    __shared__ int wsums[16];
    __shared__ int carry_s;
    int t = threadIdx.x;
    int lane = t & 63, wid = t >> 6;
    if (t == 0) { carry_s = 0; seg[0] = 0; }
    __syncthreads();
    for (int base = 0; base < Nn; base += 1024) {
        int idx = base + t;
        int v = (idx < Nn) ? hist[idx] : 0;
        int sc = v;
#pragma unroll
        for (int d = 1; d < 64; d <<= 1) {
            int up = __shfl_up(sc, d);
            if (lane >= d) sc += up;
        }
        if (lane == 63) wsums[wid] = sc;
        __syncthreads();
        if (wid == 0) {
            int wv = (lane < 16) ? wsums[lane] : 0;
            int wsc = wv;
#pragma unroll
            for (int d = 1; d < 16; d <<= 1) {
                int up = __shfl_up(wsc, d);
                if (lane >= d) wsc += up;
            }
            if (lane < 16) wsums[lane] = wsc - wv;
        }
        __syncthreads();
        int carry = carry_s;
        int inc = sc + wsums[wid] + carry;
        if (idx < Nn) { seg[idx + 1] = inc; pos[idx] = inc - v; }
        __syncthreads();
        if (t == 1023) carry_s = inc;
        __syncthreads();
    }
}

__global__ void k_scatter(const int* __restrict__ ei, int* __restrict__ pos,
                          int* __restrict__ peid, int* __restrict__ psrc) {
    int i = blockIdx.x * 256 + threadIdx.x;
    if (i >= ET) return;
    int s, d;
    if (i < Ee) { s = ei[i]; d = ei[Ee + i]; } else { s = d = i - Ee; }
    int idx = atomicAdd(&pos[d], 1);
    peid[idx] = i;
    psrc[idx] = s;
}

// ---------------- per-layer: xh = h @ lw ; als/ald = h @ Bs/Bd ----------------
__global__ __launch_bounds__(256) void k_xh(
    const float* __restrict__ h, const float* __restrict__ lw,
    const float* __restrict__ Bs, const float* __restrict__ Bd,
    float* __restrict__ xh, float* __restrict__ als, float* __restrict__ ald) {
    __shared__ float4 hs4[16][32];
    int t = threadIdx.x;
    int n0 = blockIdx.x * 16;
    for (int z = t; z < 512; z += 256) {
        int i = z >> 5, kb = z & 31;
        hs4[i][kb] = *(const float4*)(h + (size_t)(n0 + i) * 128 + 4 * kb);
    }
    __syncthreads();
    int g = t >> 7;
    int c4 = (t & 127) * 4;
    const float* lwc = lw + c4;
    float4 acc[8];
#pragma unroll
    for (int i = 0; i < 8; i++) acc[i] = make_float4(0.f, 0.f, 0.f, 0.f);
    for (int kb = 0; kb < 32; kb++) {
        float4 w0 = *(const float4*)(lwc + (size_t)(4 * kb + 0) * 512);
        float4 w1 = *(const float4*)(lwc + (size_t)(4 * kb + 1) * 512);
        float4 w2 = *(const float4*)(lwc + (size_t)(4 * kb + 2) * 512);
        float4 w3 = *(const float4*)(lwc + (size_t)(4 * kb + 3) * 512);
#pragma unroll
        for (int i = 0; i < 8; i++) {
            float4 hv = hs4[g * 8 + i][kb];
            acc[i].x += hv.x * w0.x + hv.y * w1.x + hv.z * w2.x + hv.w * w3.x;
            acc[i].y += hv.x * w0.y + hv.y * w1.y + hv.z * w2.y + hv.w * w3.y;
            acc[i].z += hv.x * w0.z + hv.y * w1.z + hv.z * w2.z + hv.w * w3.z;
            acc[i].w += hv.x * w0.w + hv.y * w1.w + hv.z * w2.w + hv.w * w3.w;
        }
    }
#pragma unroll
    for (int i = 0; i < 8; i++)
        *(float4*)(xh + (size_t)(n0 + g * 8 + i) * 512 + c4) = acc[i];
    if (t < 64) {
        int i = t >> 2, hh = t & 3;
        float s1 = 0, s2 = 0;
        for (int kb = 0; kb < 32; kb++) {
            float4 hv = hs4[i][kb];
            s1 += hv.x * Bs[(4 * kb + 0) * 4 + hh] + hv.y * Bs[(4 * kb + 1) * 4 + hh]
                + hv.z * Bs[(4 * kb + 2) * 4 + hh] + hv.w * Bs[(4 * kb + 3) * 4 + hh];
            s2 += hv.x * Bd[(4 * kb + 0) * 4 + hh] + hv.y * Bd[(4 * kb + 1) * 4 + hh]
                + hv.z * Bd[(4 * kb + 2) * 4 + hh] + hv.w * Bd[(4 * kb + 3) * 4 + hh];
        }
        als[(n0 + i) * 4 + hh] = s1;
        ald[(n0 + i) * 4 + hh] = s2;
    }
}

// ---- per-layer: segment softmax + gather-aggregate + LN. One WAVE per node, no barriers ----
__global__ __launch_bounds__(256) void k_agg(
    const int* __restrict__ peid, const int* __restrict__ psrc,
    const int* __restrict__ seg, const float* __restrict__ als,
    const float* __restrict__ ald, const float* __restrict__ ale,
    const float* __restrict__ lale, const float* __restrict__ xh,
    const float* __restrict__ bias, const float* __restrict__ lnsc,
    const float* __restrict__ lnbi, float* __restrict__ hio, int l) {
    int t = threadIdx.x;
    int lane = t & 63;
    int n = blockIdx.x * 4 + (t >> 6);
    int start = seg[n], end = seg[n + 1];
    const float* alel = ale + l * 4;
    float llv[4];
    *(float4*)llv = *(const float4*)(lale + l * 4);
    // ---- phase 1: online (max, sumexp); lane handles head h1 = lane&3, edges strided 16 ----
    int h1 = lane & 3;
    float a1d = ald[n * 4 + h1];
    float m = -INFINITY, ss = 0.f;
    for (int i = start + (lane >> 2); i < end; i += 16) {
        int s = psrc[i], e = peid[i];
        float av = als[s * 4 + h1] + a1d
                 + (e < Ee ? alel[(size_t)e * 24 + h1] : llv[h1]);
        av = av > 0.f ? av : 0.2f * av;
        if (av > m) { ss = ss * __expf(m - av) + 1.f; m = av; }
        else ss += __expf(av - m);
    }
#pragma unroll
    for (int d = 4; d <= 32; d <<= 1) {
        float mo = __shfl_xor(m, d), so = __shfl_xor(ss, d);
        float mm = fmaxf(m, mo);
        float sv = 0.f;
        if (m > -INFINITY) sv += ss * __expf(m - mm);
        if (mo > -INFINITY) sv += so * __expf(mo - mm);
        m = mm; ss = sv;
    }
    int hp = lane >> 4;                      // head owned in phase 2
    float mh = __shfl(m, hp);
    float inv = 1.f / (__shfl(ss, hp) + 1e-16f);
    float adp = ald[n * 4 + hp];
    // ---- phase 2: lane owns 8 channels c8 = lane*8 of the 512 ----
    int c8 = lane * 8;
    float4 acc0 = make_float4(0.f, 0.f, 0.f, 0.f);
    float4 acc1 = make_float4(0.f, 0.f, 0.f, 0.f);
    for (int i = start; i < end; i++) {
        int s = psrc[i], e = peid[i];
        float av = als[s * 4 + hp] + adp
                 + (e < Ee ? alel[(size_t)e * 24 + hp] : llv[hp]);
        av = av > 0.f ? av : 0.2f * av;
        float wgt = __expf(av - mh) * inv;
        const float4* xr = (const float4*)(xh + (size_t)s * 512 + c8);
        float4 x0 = xr[0], x1 = xr[1];
        acc0.x += wgt * x0.x; acc0.y += wgt * x0.y; acc0.z += wgt * x0.z; acc0.w += wgt * x0.w;
        acc1.x += wgt * x1.x; acc1.y += wgt * x1.y; acc1.z += wgt * x1.z; acc1.w += wgt * x1.w;
    }
    // ---- head mean: xor 16,32 sums the 4 heads for channel slice (lane&15)*8 ----
#pragma unroll
    for (int d = 16; d <= 32; d <<= 1) {
        acc0.x += __shfl_xor(acc0.x, d); acc0.y += __shfl_xor(acc0.y, d);
        acc0.z += __shfl_xor(acc0.z, d); acc0.w += __shfl_xor(acc0.w, d);
        acc1.x += __shfl_xor(acc1.x, d); acc1.y += __shfl_xor(acc1.y, d);
        acc1.z += __shfl_xor(acc1.z, d); acc1.w += __shfl_xor(acc1.w, d);
    }
    int cc = (lane & 15) * 8;
    float4 b0 = *(const float4*)(bias + cc), b1 = *(const float4*)(bias + cc + 4);
    float4 h0 = *(const float4*)(hio + (size_t)n * 128 + cc);
    float4 h1v = *(const float4*)(hio + (size_t)n * 128 + cc + 4);
    float4 v0, v1;
    v0.x = h0.x + fmaxf(0.25f * acc0.x + b0.x, 0.f);
    v0.y = h0.y + fmaxf(0.25f * acc0.y + b0.y, 0.f);
    v0.z = h0.z + fmaxf(0.25f * acc0.z + b0.z, 0.f);
    v0.w = h0.w + fmaxf(0.25f * acc0.w + b0.w, 0.f);
    v1.x = h1v.x + fmaxf(0.25f * acc1.x + b1.x, 0.f);
    v1.y = h1v.y + fmaxf(0.25f * acc1.y + b1.y, 0.f);
    v1.z = h1v.z + fmaxf(0.25f * acc1.z + b1.z, 0.f);
    v1.w = h1v.w + fmaxf(0.25f * acc1.w + b1.w, 0.f);
    float s1 = v0.x + v0.y + v0.z + v0.w + v1.x + v1.y + v1.z + v1.w;
    float s2 = v0.x * v0.x + v0.y * v0.y + v0.z * v0.z + v0.w * v0.w
             + v1.x * v1.x + v1.y * v1.y + v1.z * v1.z + v1.w * v1.w;
#pragma unroll
    for (int d = 1; d <= 8; d <<= 1) {
        s1 += __shfl_xor(s1, d); s2 += __shfl_xor(s2, d);
    }
    float mean = s1 * (1.f / 128.f);
    float var = s2 * (1.f / 128.f) - mean * mean;
    float rinv = rsqrtf(var + 1e-5f);
    if (lane < 16) {
        float4 ls0 = *(const float4*)(lnsc + cc), ls1 = *(const float4*)(lnsc + cc + 4);
        float4 lb0 = *(const float4*)(lnbi + cc), lb1 = *(const float4*)(lnbi + cc + 4);
        float4 o0, o1;
        o0.x = (v0.x - mean) * rinv * ls0.x + lb0.x;
        o0.y = (v0.y - mean) * rinv * ls0.y + lb0.y;
        o0.z = (v0.z - mean) * rinv * ls0.z + lb0.z;
        o0.w = (v0.w - mean) * rinv * ls0.w + lb0.w;
        o1.x = (v1.x - mean) * rinv * ls1.x + lb1.x;
        o1.y = (v1.y - mean) * rinv * ls1.y + lb1.y;
        o1.z = (v1.z - mean) * rinv * ls1.z + lb1.z;
        o1.w = (v1.w - mean) * rinv * ls1.w + lb1.w;
        *(float4*)(hio + (size_t)n * 128 + cc) = o0;
        *(float4*)(hio + (size_t)n * 128 + cc + 4) = o1;
    }
}

// ---------------- output projection ----------------
__global__ __launch_bounds__(256) void k_out(
    const float* __restrict__ h, const float* __restrict__ ow,
    const float* __restrict__ ob, float* __restrict__ out) {
    __shared__ float4 hs4[8][32];
    int t = threadIdx.x;
    int n0 = blockIdx.x * 8;
    if (t < 256) {
        int i = t >> 5, kb = t & 31;
        hs4[i][kb] = *(const float4*)(h + (size_t)(n0 + i) * 128 + 4 * kb);
    }
    __syncthreads();
    float acc[8] = {0, 0, 0, 0, 0, 0, 0, 0};
    for (int kb = 0; kb < 32; kb++) {
        float w0 = ow[(4 * kb + 0) * 256 + t];
        float w1 = ow[(4 * kb + 1) * 256 + t];
        float w2 = ow[(4 * kb + 2) * 256 + t];
        float w3 = ow[(4 * kb + 3) * 256 + t];
#pragma unroll
        for (int i = 0; i < 8; i++) {
            float4 hv = hs4[i][kb];
            acc[i] += hv.x * w0 + hv.y * w1 + hv.z * w2 + hv.w * w3;
        }
    }
    float b = ob[t];
#pragma unroll
    for (int i = 0; i < 8; i++) out[(size_t)(n0 + i) * 256 + t] = acc[i] + b;
}

extern "C" void kernel_launch(void* const* d_in, const int* in_sizes, int n_in,
                              void* d_out, int out_size, void* d_ws, size_t ws_size,
                              hipStream_t stream) {
    const float* x    = (const float*)d_in[0];
    const int*   ei   = (const int*)d_in[1];
    const float* ea   = (const float*)d_in[2];
    const float* vnfc = (const float*)d_in[3];
    const float* nw   = (const float*)d_in[4];
    const float* nb   = (const float*)d_in[5];
    const float* eaw  = (const float*)d_in[6];
    const float* eab  = (const float*)d_in[7];
    const float* vw   = (const float*)d_in[8];
    const float* vb   = (const float*)d_in[9];
    const float* a1w  = (const float*)d_in[10];
    const float* a1b  = (const float*)d_in[11];
    const float* a2w  = (const float*)d_in[12];
    const float* a2b  = (const float*)d_in[13];
    const float* a3w  = (const float*)d_in[14];
    const float* a3b  = (const float*)d_in[15];
    const float* glw  = (const float*)d_in[16];
    const float* gas  = (const float*)d_in[17];
    const float* gad  = (const float*)d_in[18];
    const float* glew = (const float*)d_in[19];
    const float* gae  = (const float*)d_in[20];
    const float* gb   = (const float*)d_in[21];
    const float* lnsc = (const float*)d_in[22];
    const float* lnbi = (const float*)d_in[23];
    const float* ow   = (const float*)d_in[24];
    const float* ob   = (const float*)d_in[25];
    float* out = (float*)d_out;

    char* w = (char*)d_ws;
    size_t o = 0;
    auto allocf = [&](size_t cnt) { float* p = (float*)(w + o); o += ((cnt * 4 + 255) / 256) * 256; return p; };
    auto alloci = [&](size_t cnt) { int* p = (int*)(w + o); o += ((cnt * 4 + 255) / 256) * 256; return p; };
    float* h      = allocf((size_t)Nn * 128);
    float* xh     = allocf((size_t)Nn * 512);
    float* als    = allocf((size_t)Nn * 4);
    float* ald    = allocf((size_t)Nn * 4);
    float* ale    = allocf((size_t)Ee * 24);
    float* Bs     = allocf(3072);
    float* Bd     = allocf(3072);
    float* Be     = allocf(3072);
    float* E1     = allocf(1024);
    float* PB     = allocf(96);
    float* cB     = allocf(24);
    float* gsum   = allocf(8);
    float* lale   = allocf(32);
    int* seg  = alloci(Nn + 1);
    int* hist = alloci(Nn);
    int* pos  = alloci(Nn);
    int* peid = alloci(ET);
    int* psrc = alloci(ET);

    hipMemsetAsync(hist, 0, Nn * sizeof(int), stream);
    hipMemsetAsync(gsum, 0, 8 * sizeof(float), stream);

    k_node_embed<<<(Nn * 128 + 255) / 256, 256, 0, stream>>>(x, nw, nb, h);
    k_small<<<1, 512, 0, stream>>>(vnfc, vw, vb, eab, a1w, a1b, eaw, E1);
    k_bmat<<<(LL * 128 * 4 + 255) / 256, 256, 0, stream>>>(glw, gas, gad, glew, gae, Bs, Bd, Be);
    k_pb<<<1, 32, 0, stream>>>(eaw, eab, Be, PB, cB);
    k_edge<<<Ee / 128, 256, 0, stream>>>(ea, E1, a2w, a2b, a3w, a3b, PB, cB, ale, gsum);
    k_hist<<<(ET + 255) / 256, 256, 0, stream>>>(ei, hist);
    k_scan<<<1, 1024, 0, stream>>>(hist, seg, pos);
    k_scatter<<<(ET + 255) / 256, 256, 0, stream>>>(ei, pos, peid, psrc);
    k_lale<<<1, 32, 0, stream>>>(gsum, PB, cB, lale);
    for (int l = 0; l < LL; l++) {
        k_xh<<<Nn / 16, 256, 0, stream>>>(h, glw + (size_t)l * 65536, Bs + l * 512, Bd + l * 512,
                                          xh, als, ald);
        k_agg<<<Nn / 4, 256, 0, stream>>>(peid, psrc, seg, als, ald, ale, lale, xh,
                                          gb + l * 128, lnsc + l * 128, lnbi + l * 128, h, l);
    }
    k_out<<<Nn / 8, 256, 0, stream>>>(h, ow, ob, out);
}

// Round 5
// 808.970 us; speedup vs baseline: 1.4187x; 1.0812x over previous
//
#include <hip/hip_runtime.h>
#include <hip/hip_bf16.h>
#include <math.h>

#define Nn 10000
#define Ee 160000
#define ET 170000   // Ee + Nn (self loops)
#define LL 6

// ---------------- node embedding: h = x @ node_w + node_b ----------------
__global__ void k_node_embed(const float* __restrict__ x, const float* __restrict__ nw,
                             const float* __restrict__ nb, float* __restrict__ h) {
    int idx = blockIdx.x * 256 + threadIdx.x;
    if (idx >= Nn * 128) return;
    int n = idx >> 7, c = idx & 127;
    const float* xr = x + (size_t)n * 8;
    float acc = nb[c];
#pragma unroll
    for (int k = 0; k < 8; k++) acc += xr[k] * nw[k * 128 + c];
    h[idx] = acc;
}

// ---------------- small precompute: E1[128][8] = {M1[0..3][k], d1[k], 0,0,0} ----------------
__global__ void k_small(const float* __restrict__ vnfc, const float* __restrict__ vw,
                        const float* __restrict__ vb, const float* __restrict__ eab,
                        const float* __restrict__ a1w, const float* __restrict__ a1b,
                        const float* __restrict__ eaw, float* __restrict__ E1) {
    __shared__ float vr[128];
    __shared__ float sM1[512];
    __shared__ float sd1[128];
    int t = threadIdx.x;   // 512
    if (t < 128) {
        float a = vb[t];
#pragma unroll
        for (int k = 0; k < 6; k++) a += vnfc[k] * vw[k * 128 + t];
        vr[t] = a;
    }
    __syncthreads();
    if (t < 128) {
        float a = a1b[t];
        for (int k = 0; k < 128; k++) a += eab[k] * a1w[k * 128 + t];
        for (int k = 0; k < 128; k++) a += vr[k] * a1w[(128 + k) * 128 + t];
        sd1[t] = a;
    }
    {
        int r = t >> 7, j = t & 127;
        float a = 0.f;
        for (int k = 0; k < 128; k++) a += eaw[r * 128 + k] * a1w[k * 128 + j];
        sM1[r * 128 + j] = a;
    }
    __syncthreads();
    if (t < 128) {
        E1[t * 8 + 0] = sM1[t];
        E1[t * 8 + 1] = sM1[128 + t];
        E1[t * 8 + 2] = sM1[256 + t];
        E1[t * 8 + 3] = sM1[384 + t];
        E1[t * 8 + 4] = sd1[t];
        E1[t * 8 + 5] = 0.f; E1[t * 8 + 6] = 0.f; E1[t * 8 + 7] = 0.f;
    }
}

// ---------------- B matrices: Bs/Bd/Be [L][128][4] ----------------
__global__ void k_bmat(const float* __restrict__ glw, const float* __restrict__ gas,
                       const float* __restrict__ gad, const float* __restrict__ glew,
                       const float* __restrict__ gae, float* __restrict__ Bs,
                       float* __restrict__ Bd, float* __restrict__ Be) {
    int idx = blockIdx.x * 256 + threadIdx.x;
    if (idx >= LL * 128 * 4) return;
    int hh = idx & 3, k = (idx >> 2) & 127, l = idx >> 9;
    const float* lwp = glw  + (size_t)l * 65536 + k * 512 + hh * 128;
    const float* lep = glew + (size_t)l * 65536 + k * 512 + hh * 128;
    const float* sp = gas + l * 512 + hh * 128;
    const float* dp = gad + l * 512 + hh * 128;
    const float* ep = gae + l * 512 + hh * 128;
    float s1 = 0, s2 = 0, s3 = 0;
    for (int c = 0; c < 128; c++) {
        float lv = lwp[c];
        s1 += lv * sp[c];
        s2 += lv * dp[c];
        s3 += lep[c] * ep[c];
    }
    Bs[idx] = s1; Bd[idx] = s2; Be[idx] = s3;
}

// ---------------- PB[4][24], cB[24]: fold ea_proj through Be ----------------
__global__ void k_pb(const float* __restrict__ eaw, const float* __restrict__ eab,
                     const float* __restrict__ Be, float* __restrict__ PB,
                     float* __restrict__ cB) {
    int t = threadIdx.x;
    if (t >= 24) return;
    int l = t >> 2, hh = t & 3;
    const float* bp = Be + l * 512 + hh;
    float s0 = 0, s1 = 0, s2 = 0, s3 = 0, sc = 0;
    for (int k = 0; k < 128; k++) {
        float bv = bp[k * 4];
        s0 += eaw[0 * 128 + k] * bv;
        s1 += eaw[1 * 128 + k] * bv;
        s2 += eaw[2 * 128 + k] * bv;
        s3 += eaw[3 * 128 + k] * bv;
        sc += eab[k] * bv;
    }
    PB[0 * 24 + t] = s0; PB[1 * 24 + t] = s1;
    PB[2 * 24 + t] = s2; PB[3 * 24 + t] = s3;
    cB[t] = sc;
}

// ---- edge gate MLP: LDS-staged weights; 128 edges/block, 2/lane, 4 waves split j ----
__global__ __launch_bounds__(256) void k_edge(
    const float* __restrict__ ea, const float* __restrict__ E1,
    const float* __restrict__ a2w, const float* __restrict__ a2b,
    const float* __restrict__ a3w, const float* __restrict__ a3b,
    const float* __restrict__ PB, const float* __restrict__ cB,
    float* __restrict__ aleT, float* __restrict__ gsum) {
    __shared__ float sw2[128 * 64];   // 32 KB, [k][j]
    __shared__ float4 sM[128];        // 2 KB
    __shared__ float sD[128];         // 512 B
    __shared__ float prs[4][128];
    __shared__ float gsh[128];
    int t = threadIdx.x;
    int lane = t & 63;
    int p = t >> 6;
    int ps = __builtin_amdgcn_readfirstlane(p);
    // stage weights
    for (int z = t; z < 2048; z += 256) ((float4*)sw2)[z] = ((const float4*)a2w)[z];
    if (t < 128) { sM[t] = *(const float4*)(E1 + t * 8); sD[t] = E1[t * 8 + 4]; }
    __syncthreads();
    int e0 = blockIdx.x * 128 + lane;
    int e1 = e0 + 64;
    float4 ev0 = *(const float4*)(ea + (size_t)e0 * 4);
    float4 ev1 = *(const float4*)(ea + (size_t)e1 * 4);
    float acc0[16], acc1[16];
#pragma unroll
    for (int j = 0; j < 16; j++) { float b = a2b[ps * 16 + j]; acc0[j] = b; acc1[j] = b; }
    const float* w2base = sw2 + ps * 16;
#pragma unroll 2
    for (int k = 0; k < 128; k++) {
        float4 m = sM[k];
        float dk = sD[k];
        float x0 = fmaxf(dk + ev0.x * m.x + ev0.y * m.y + ev0.z * m.z + ev0.w * m.w, 0.f);
        float x1 = fmaxf(dk + ev1.x * m.x + ev1.y * m.y + ev1.z * m.z + ev1.w * m.w, 0.f);
        const float* w2r = w2base + k * 64;
#pragma unroll
        for (int j4 = 0; j4 < 4; j4++) {
            float4 wv = *(const float4*)(w2r + j4 * 4);
            acc0[4 * j4 + 0] += x0 * wv.x; acc1[4 * j4 + 0] += x1 * wv.x;
            acc0[4 * j4 + 1] += x0 * wv.y; acc1[4 * j4 + 1] += x1 * wv.y;
            acc0[4 * j4 + 2] += x0 * wv.z; acc1[4 * j4 + 2] += x1 * wv.z;
            acc0[4 * j4 + 3] += x0 * wv.w; acc1[4 * j4 + 3] += x1 * wv.w;
        }
    }
    float pr0 = 0.f, pr1 = 0.f;
#pragma unroll
    for (int j = 0; j < 16; j++) {
        float w3 = a3w[ps * 16 + j];
        pr0 += fmaxf(acc0[j], 0.f) * w3;
        pr1 += fmaxf(acc1[j], 0.f) * w3;
    }
    prs[p][lane] = pr0; prs[p][64 + lane] = pr1;
    __syncthreads();
    if (p == 0) {
        float v0 = 0.f, v1 = 0.f, v2 = 0.f, v3 = 0.f, v4 = 0.f;
#pragma unroll
        for (int rep = 0; rep < 2; rep++) {
            int le = rep * 64 + lane;
            float tot = prs[0][le] + prs[1][le] + prs[2][le] + prs[3][le] + a3b[0];
            float g = 1.f / (1.f + __expf(-tot));
            gsh[le] = g;
            float4 evv = rep == 0 ? ev0 : ev1;
            v0 += g; v1 += g * evv.x; v2 += g * evv.y; v3 += g * evv.z; v4 += g * evv.w;
        }
#pragma unroll
        for (int d = 32; d > 0; d >>= 1) {
            v0 += __shfl_down(v0, d); v1 += __shfl_down(v1, d); v2 += __shfl_down(v2, d);
            v3 += __shfl_down(v3, d); v4 += __shfl_down(v4, d);
        }
        if (lane == 0) {
            atomicAdd(&gsum[0], v0); atomicAdd(&gsum[1], v1); atomicAdd(&gsum[2], v2);
            atomicAdd(&gsum[3], v3); atomicAdd(&gsum[4], v4);
        }
    }
    __syncthreads();
    float g0 = gsh[lane], g1 = gsh[64 + lane];
#pragma unroll
    for (int rep = 0; rep < 2; rep++) {
        int i4 = (rep == 0) ? ps : (ps < 2 ? ps + 4 : -1);
        if (i4 >= 0) {
            float4 c  = *(const float4*)(cB + i4 * 4);
            float4 p0 = *(const float4*)(PB + 0 * 24 + i4 * 4);
            float4 p1 = *(const float4*)(PB + 1 * 24 + i4 * 4);
            float4 p2 = *(const float4*)(PB + 2 * 24 + i4 * 4);
            float4 p3 = *(const float4*)(PB + 3 * 24 + i4 * 4);
            float4 o;
            o.x = g0 * (c.x + ev0.x * p0.x + ev0.y * p1.x + ev0.z * p2.x + ev0.w * p3.x);
            o.y = g0 * (c.y + ev0.x * p0.y + ev0.y * p1.y + ev0.z * p2.y + ev0.w * p3.y);
            o.z = g0 * (c.z + ev0.x * p0.z + ev0.y * p1.z + ev0.z * p2.z + ev0.w * p3.z);
            o.w = g0 * (c.w + ev0.x * p0.w + ev0.y * p1.w + ev0.z * p2.w + ev0.w * p3.w);
            *(float4*)(aleT + (size_t)i4 * Ee * 4 + (size_t)e0 * 4) = o;
            float4 q;
            q.x = g1 * (c.x + ev1.x * p0.x + ev1.y * p1.x + ev1.z * p2.x + ev1.w * p3.x);
            q.y = g1 * (c.y + ev1.x * p0.y + ev1.y * p1.y + ev1.z * p2.y + ev1.w * p3.y);
            q.z = g1 * (c.z + ev1.x * p0.z + ev1.y * p1.z + ev1.z * p2.z + ev1.w * p3.z);
            q.w = g1 * (c.w + ev1.x * p0.w + ev1.y * p1.w + ev1.z * p2.w + ev1.w * p3.w);
            *(float4*)(aleT + (size_t)i4 * Ee * 4 + (size_t)e1 * 4) = q;
        }
    }
}

// ---------------- loop-edge al_e from G,S sums ----------------
__global__ void k_lale(const float* __restrict__ gsum, const float* __restrict__ PB,
                       const float* __restrict__ cB, float* __restrict__ lale) {
    int t = threadIdx.x;
    if (t >= 24) return;
    float s = gsum[0] * cB[t] + gsum[1] * PB[t] + gsum[2] * PB[24 + t]
            + gsum[3] * PB[48 + t] + gsum[4] * PB[72 + t];
    lale[t] = s * (1.0f / Ee);
}

// ---------------- counting sort by dst: hist / scan / scatter ----------------
__global__ void k_hist(const int* __restrict__ ei, int* __restrict__ hist) {
    int i = blockIdx.x * 256 + threadIdx.x;
    if (i >= ET) return;
    int d = (i < Ee) ? ei[Ee + i] : (i - Ee);
    atomicAdd(&hist[d], 1);
}

__global__ __launch_bounds__(1024) void k_scan(const int* __restrict__ hist,
                                               int* __restrict__ seg, int* __restrict__ pos) {
    __shared__ int wsums[16];
    __shared__ int carry_s;
    int t = threadIdx.x;
    int lane = t & 63, wid = t >> 6;
    if (t == 0) { carry_s = 0; seg[0] = 0; }
    __syncthreads();
    for (int base = 0; base < Nn; base += 1024) {
        int idx = base + t;
        int v = (idx < Nn) ? hist[idx] : 0;
        int sc = v;
#pragma unroll
        for (int d = 1; d < 64; d <<= 1) {
            int up = __shfl_up(sc, d);
            if (lane >= d) sc += up;
        }
        if (lane == 63) wsums[wid] = sc;
        __syncthreads();
        if (wid == 0) {
            int wv = (lane < 16) ? wsums[lane] : 0;
            int wsc = wv;
#pragma unroll
            for (int d = 1; d < 16; d <<= 1) {
                int up = __shfl_up(wsc, d);
                if (lane >= d) wsc += up;
            }
            if (lane < 16) wsums[lane] = wsc - wv;
        }
        __syncthreads();
        int carry = carry_s;
        int inc = sc + wsums[wid] + carry;
        if (idx < Nn) { seg[idx + 1] = inc; pos[idx] = inc - v; }
        __syncthreads();
        if (t == 1023) carry_s = inc;
        __syncthreads();
    }
}

__global__ void k_scatter(const int* __restrict__ ei, int* __restrict__ pos,
                          int2* __restrict__ pse) {
    int i = blockIdx.x * 256 + threadIdx.x;
    if (i >= ET) return;
    int s, d;
    if (i < Ee) { s = ei[i]; d = ei[Ee + i]; } else { s = d = i - Ee; }
    int idx = atomicAdd(&pos[d], 1);
    pse[idx] = make_int2(s, i);
}

// ---------------- per-layer: xh = h @ lw ; als/ald = h @ Bs/Bd ----------------
__global__ __launch_bounds__(512) void k_xh(
    const float* __restrict__ h, const float* __restrict__ lw,
    const float* __restrict__ Bs, const float* __restrict__ Bd,
    float* __restrict__ xh, float* __restrict__ als, float* __restrict__ ald) {
    __shared__ float4 hs4[16][32];
    int t = threadIdx.x;   // 512
    int n0 = blockIdx.x * 16;
    {
        int i = t >> 5, kb = t & 31;
        hs4[i][kb] = *(const float4*)(h + (size_t)(n0 + i) * 128 + 4 * kb);
    }
    __syncthreads();
    int g = t >> 7;              // 0..3 -> rows g*4..g*4+3
    int c4 = (t & 127) * 4;
    const float* lwc = lw + c4;
    float4 acc[4];
#pragma unroll
    for (int i = 0; i < 4; i++) acc[i] = make_float4(0.f, 0.f, 0.f, 0.f);
    for (int kb = 0; kb < 32; kb++) {
        float4 w0 = *(const float4*)(lwc + (size_t)(4 * kb + 0) * 512);
        float4 w1 = *(const float4*)(lwc + (size_t)(4 * kb + 1) * 512);
        float4 w2 = *(const float4*)(lwc + (size_t)(4 * kb + 2) * 512);
        float4 w3 = *(const float4*)(lwc + (size_t)(4 * kb + 3) * 512);
#pragma unroll
        for (int i = 0; i < 4; i++) {
            float4 hv = hs4[g * 4 + i][kb];
            acc[i].x += hv.x * w0.x + hv.y * w1.x + hv.z * w2.x + hv.w * w3.x;
            acc[i].y += hv.x * w0.y + hv.y * w1.y + hv.z * w2.y + hv.w * w3.y;
            acc[i].z += hv.x * w0.z + hv.y * w1.z + hv.z * w2.z + hv.w * w3.z;
            acc[i].w += hv.x * w0.w + hv.y * w1.w + hv.z * w2.w + hv.w * w3.w;
        }
    }
#pragma unroll
    for (int i = 0; i < 4; i++)
        *(float4*)(xh + (size_t)(n0 + g * 4 + i) * 512 + c4) = acc[i];
    if (t < 64) {
        int i = t >> 2, hh = t & 3;
        float s1 = 0, s2 = 0;
        for (int kb = 0; kb < 32; kb++) {
            float4 hv = hs4[i][kb];
            s1 += hv.x * Bs[(4 * kb + 0) * 4 + hh] + hv.y * Bs[(4 * kb + 1) * 4 + hh]
                + hv.z * Bs[(4 * kb + 2) * 4 + hh] + hv.w * Bs[(4 * kb + 3) * 4 + hh];
            s2 += hv.x * Bd[(4 * kb + 0) * 4 + hh] + hv.y * Bd[(4 * kb + 1) * 4 + hh]
                + hv.z * Bd[(4 * kb + 2) * 4 + hh] + hv.w * Bd[(4 * kb + 3) * 4 + hh];
        }
        als[(n0 + i) * 4 + hh] = s1;
        ald[(n0 + i) * 4 + hh] = s2;
    }
}

// ---- per-layer: wave per node; weights staged in LDS, unrolled xh gather ----
__global__ __launch_bounds__(256) void k_agg(
    const int2* __restrict__ pse, const int* __restrict__ seg,
    const float* __restrict__ als, const float* __restrict__ ald,
    const float* __restrict__ aleT, const float* __restrict__ lale_l,
    const float* __restrict__ xh, const float* __restrict__ bias,
    const float* __restrict__ lnsc, const float* __restrict__ lnbi,
    float* __restrict__ hio) {
    __shared__ float wgtS[4][256];
    __shared__ int srcS[4][64];
    int t = threadIdx.x;
    int lane = t & 63;
    int w = t >> 6;
    int n = blockIdx.x * 4 + w;
    int start = seg[n], end = seg[n + 1];
    float4 llv4 = *(const float4*)lale_l;
    // ---- phase 1: online (max, sumexp); lane -> head lane&3, edges strided 16 ----
    int h1 = lane & 3;
    float llh1 = h1 == 0 ? llv4.x : h1 == 1 ? llv4.y : h1 == 2 ? llv4.z : llv4.w;
    float a1d = ald[n * 4 + h1];
    float m = -INFINITY, ss = 0.f;
    for (int i = start + (lane >> 2); i < end; i += 16) {
        int2 se = pse[i];
        float alev = se.y < Ee ? aleT[(size_t)se.y * 4 + h1] : llh1;
        float av = als[se.x * 4 + h1] + a1d + alev;
        av = av > 0.f ? av : 0.2f * av;
        if (av > m) { ss = ss * __expf(m - av) + 1.f; m = av; }
        else ss += __expf(av - m);
    }
#pragma unroll
    for (int d = 4; d <= 32; d <<= 1) {
        float mo = __shfl_xor(m, d), so = __shfl_xor(ss, d);
        float mm = fmaxf(m, mo);
        float sv = 0.f;
        if (m > -INFINITY) sv += ss * __expf(m - mm);
        if (mo > -INFINITY) sv += so * __expf(mo - mm);
        m = mm; ss = sv;
    }
    float mh0 = __shfl(m, 0), mh1 = __shfl(m, 1), mh2 = __shfl(m, 2), mh3 = __shfl(m, 3);
    float iv0 = 1.f / (__shfl(ss, 0) + 1e-16f), iv1 = 1.f / (__shfl(ss, 1) + 1e-16f);
    float iv2 = 1.f / (__shfl(ss, 2) + 1e-16f), iv3 = 1.f / (__shfl(ss, 3) + 1e-16f);
    float4 ald4 = *(const float4*)(ald + n * 4);
    int hp = lane >> 4;   // head owned in gather
    int c8 = lane * 8;    // wait: need (lane&15)*8 within head's 128 chans... see below
    // lane owns channels [hp*128 + (lane&15)*8 .. +8) of the 512 = exactly lane*8
    float4 acc0 = make_float4(0.f, 0.f, 0.f, 0.f);
    float4 acc1 = make_float4(0.f, 0.f, 0.f, 0.f);
    for (int cb = start; cb < end; cb += 64) {
        int cnt = min(64, end - cb);
        if (lane < cnt) {
            int2 se = pse[cb + lane];
            float4 alev = se.y < Ee ? *(const float4*)(aleT + (size_t)se.y * 4) : llv4;
            float4 as4 = *(const float4*)(als + se.x * 4);
            float av0 = as4.x + ald4.x + alev.x;
            float av1 = as4.y + ald4.y + alev.y;
            float av2 = as4.z + ald4.z + alev.z;
            float av3 = as4.w + ald4.w + alev.w;
            av0 = av0 > 0.f ? av0 : 0.2f * av0;
            av1 = av1 > 0.f ? av1 : 0.2f * av1;
            av2 = av2 > 0.f ? av2 : 0.2f * av2;
            av3 = av3 > 0.f ? av3 : 0.2f * av3;
            float4 wg;
            wg.x = __expf(av0 - mh0) * iv0;
            wg.y = __expf(av1 - mh1) * iv1;
            wg.z = __expf(av2 - mh2) * iv2;
            wg.w = __expf(av3 - mh3) * iv3;
            *(float4*)&wgtS[w][lane * 4] = wg;
            srcS[w][lane] = se.x;
        }
        int i2 = 0;
        for (; i2 + 2 <= cnt; i2 += 2) {
            int s0 = srcS[w][i2], s1 = srcS[w][i2 + 1];
            float wg0 = wgtS[w][i2 * 4 + hp], wg1 = wgtS[w][i2 * 4 + 4 + hp];
            const float4* xr0 = (const float4*)(xh + (size_t)s0 * 512 + c8);
            const float4* xr1 = (const float4*)(xh + (size_t)s1 * 512 + c8);
            float4 a0 = xr0[0], b0 = xr0[1];
            float4 a1 = xr1[0], b1 = xr1[1];
            acc0.x += wg0 * a0.x + wg1 * a1.x; acc0.y += wg0 * a0.y + wg1 * a1.y;
            acc0.z += wg0 * a0.z + wg1 * a1.z; acc0.w += wg0 * a0.w + wg1 * a1.w;
            acc1.x += wg0 * b0.x + wg1 * b1.x; acc1.y += wg0 * b0.y + wg1 * b1.y;
            acc1.z += wg0 * b0.z + wg1 * b1.z; acc1.w += wg0 * b0.w + wg1 * b1.w;
        }
        if (i2 < cnt) {
            int s0 = srcS[w][i2];
            float wg0 = wgtS[w][i2 * 4 + hp];
            const float4* xr0 = (const float4*)(xh + (size_t)s0 * 512 + c8);
            float4 a0 = xr0[0], b0 = xr0[1];
            acc0.x += wg0 * a0.x; acc0.y += wg0 * a0.y;
            acc0.z += wg0 * a0.z; acc0.w += wg0 * a0.w;
            acc1.x += wg0 * b0.x; acc1.y += wg0 * b0.y;
            acc1.z += wg0 * b0.z; acc1.w += wg0 * b0.w;
        }
    }
    // ---- head mean: xor 16,32 sums the 4 heads for channel slice (lane&15)*8 ----
#pragma unroll
    for (int d = 16; d <= 32; d <<= 1) {
        acc0.x += __shfl_xor(acc0.x, d); acc0.y += __shfl_xor(acc0.y, d);
        acc0.z += __shfl_xor(acc0.z, d); acc0.w += __shfl_xor(acc0.w, d);
        acc1.x += __shfl_xor(acc1.x, d); acc1.y += __shfl_xor(acc1.y, d);
        acc1.z += __shfl_xor(acc1.z, d); acc1.w += __shfl_xor(acc1.w, d);
    }
    int cc = (lane & 15) * 8;
    float4 b0 = *(const float4*)(bias + cc), b1 = *(const float4*)(bias + cc + 4);
    float4 h0 = *(const float4*)(hio + (size_t)n * 128 + cc);
    float4 h1v = *(const float4*)(hio + (size_t)n * 128 + cc + 4);
    float4 v0, v1;
    v0.x = h0.x + fmaxf(0.25f * acc0.x + b0.x, 0.f);
    v0.y = h0.y + fmaxf(0.25f * acc0.y + b0.y, 0.f);
    v0.z = h0.z + fmaxf(0.25f * acc0.z + b0.z, 0.f);
    v0.w = h0.w + fmaxf(0.25f * acc0.w + b0.w, 0.f);
    v1.x = h1v.x + fmaxf(0.25f * acc1.x + b1.x, 0.f);
    v1.y = h1v.y + fmaxf(0.25f * acc1.y + b1.y, 0.f);
    v1.z = h1v.z + fmaxf(0.25f * acc1.z + b1.z, 0.f);
    v1.w = h1v.w + fmaxf(0.25f * acc1.w + b1.w, 0.f);
    float s1 = v0.x + v0.y + v0.z + v0.w + v1.x + v1.y + v1.z + v1.w;
    float s2 = v0.x * v0.x + v0.y * v0.y + v0.z * v0.z + v0.w * v0.w
             + v1.x * v1.x + v1.y * v1.y + v1.z * v1.z + v1.w * v1.w;
#pragma unroll
    for (int d = 1; d <= 8; d <<= 1) {
        s1 += __shfl_xor(s1, d); s2 += __shfl_xor(s2, d);
    }
    float mean = s1 * (1.f / 128.f);
    float var = s2 * (1.f / 128.f) - mean * mean;
    float rinv = rsqrtf(var + 1e-5f);
    if (lane < 16) {
        float4 ls0 = *(const float4*)(lnsc + cc), ls1 = *(const float4*)(lnsc + cc + 4);
        float4 lb0 = *(const float4*)(lnbi + cc), lb1 = *(const float4*)(lnbi + cc + 4);
        float4 o0, o1;
        o0.x = (v0.x - mean) * rinv * ls0.x + lb0.x;
        o0.y = (v0.y - mean) * rinv * ls0.y + lb0.y;
        o0.z = (v0.z - mean) * rinv * ls0.z + lb0.z;
        o0.w = (v0.w - mean) * rinv * ls0.w + lb0.w;
        o1.x = (v1.x - mean) * rinv * ls1.x + lb1.x;
        o1.y = (v1.y - mean) * rinv * ls1.y + lb1.y;
        o1.z = (v1.z - mean) * rinv * ls1.z + lb1.z;
        o1.w = (v1.w - mean) * rinv * ls1.w + lb1.w;
        *(float4*)(hio + (size_t)n * 128 + cc) = o0;
        *(float4*)(hio + (size_t)n * 128 + cc + 4) = o1;
    }
}

// ---------------- output projection ----------------
__global__ __launch_bounds__(256) void k_out(
    const float* __restrict__ h, const float* __restrict__ ow,
    const float* __restrict__ ob, float* __restrict__ out) {
    __shared__ float4 hs4[8][32];
    int t = threadIdx.x;
    int n0 = blockIdx.x * 8;
    if (t < 256) {
        int i = t >> 5, kb = t & 31;
        hs4[i][kb] = *(const float4*)(h + (size_t)(n0 + i) * 128 + 4 * kb);
    }
    __syncthreads();
    float acc[8] = {0, 0, 0, 0, 0, 0, 0, 0};
    for (int kb = 0; kb < 32; kb++) {
        float w0 = ow[(4 * kb + 0) * 256 + t];
        float w1 = ow[(4 * kb + 1) * 256 + t];
        float w2 = ow[(4 * kb + 2) * 256 + t];
        float w3 = ow[(4 * kb + 3) * 256 + t];
#pragma unroll
        for (int i = 0; i < 8; i++) {
            float4 hv = hs4[i][kb];
            acc[i] += hv.x * w0 + hv.y * w1 + hv.z * w2 + hv.w * w3;
        }
    }
    float b = ob[t];
#pragma unroll
    for (int i = 0; i < 8; i++) out[(size_t)(n0 + i) * 256 + t] = acc[i] + b;
}

extern "C" void kernel_launch(void* const* d_in, const int* in_sizes, int n_in,
                              void* d_out, int out_size, void* d_ws, size_t ws_size,
                              hipStream_t stream) {
    const float* x    = (const float*)d_in[0];
    const int*   ei   = (const int*)d_in[1];
    const float* ea   = (const float*)d_in[2];
    const float* vnfc = (const float*)d_in[3];
    const float* nw   = (const float*)d_in[4];
    const float* nb   = (const float*)d_in[5];
    const float* eaw  = (const float*)d_in[6];
    const float* eab  = (const float*)d_in[7];
    const float* vw   = (const float*)d_in[8];
    const float* vb   = (const float*)d_in[9];
    const float* a1w  = (const float*)d_in[10];
    const float* a1b  = (const float*)d_in[11];
    const float* a2w  = (const float*)d_in[12];
    const float* a2b  = (const float*)d_in[13];
    const float* a3w  = (const float*)d_in[14];
    const float* a3b  = (const float*)d_in[15];
    const float* glw  = (const float*)d_in[16];
    const float* gas  = (const float*)d_in[17];
    const float* gad  = (const float*)d_in[18];
    const float* glew = (const float*)d_in[19];
    const float* gae  = (const float*)d_in[20];
    const float* gb   = (const float*)d_in[21];
    const float* lnsc = (const float*)d_in[22];
    const float* lnbi = (const float*)d_in[23];
    const float* ow   = (const float*)d_in[24];
    const float* ob   = (const float*)d_in[25];
    float* out = (float*)d_out;

    char* w = (char*)d_ws;
    size_t o = 0;
    auto allocf = [&](size_t cnt) { float* p = (float*)(w + o); o += ((cnt * 4 + 255) / 256) * 256; return p; };
    auto alloci = [&](size_t cnt) { int* p = (int*)(w + o); o += ((cnt * 4 + 255) / 256) * 256; return p; };
    float* h      = allocf((size_t)Nn * 128);
    float* xh     = allocf((size_t)Nn * 512);
    float* als    = allocf((size_t)Nn * 4);
    float* ald    = allocf((size_t)Nn * 4);
    float* aleT   = allocf((size_t)LL * Ee * 4);
    float* Bs     = allocf(3072);
    float* Bd     = allocf(3072);
    float* Be     = allocf(3072);
    float* E1     = allocf(1024);
    float* PB     = allocf(96);
    float* cB     = allocf(24);
    float* gsum   = allocf(8);
    float* lale   = allocf(32);
    int* seg  = alloci(Nn + 1);
    int* hist = alloci(Nn);
    int* pos  = alloci(Nn);
    int2* pse = (int2*)alloci((size_t)ET * 2);

    hipMemsetAsync(hist, 0, Nn * sizeof(int), stream);
    hipMemsetAsync(gsum, 0, 8 * sizeof(float), stream);

    k_node_embed<<<(Nn * 128 + 255) / 256, 256, 0, stream>>>(x, nw, nb, h);
    k_small<<<1, 512, 0, stream>>>(vnfc, vw, vb, eab, a1w, a1b, eaw, E1);
    k_bmat<<<(LL * 128 * 4 + 255) / 256, 256, 0, stream>>>(glw, gas, gad, glew, gae, Bs, Bd, Be);
    k_pb<<<1, 32, 0, stream>>>(eaw, eab, Be, PB, cB);
    k_edge<<<Ee / 128, 256, 0, stream>>>(ea, E1, a2w, a2b, a3w, a3b, PB, cB, aleT, gsum);
    k_hist<<<(ET + 255) / 256, 256, 0, stream>>>(ei, hist);
    k_scan<<<1, 1024, 0, stream>>>(hist, seg, pos);
    k_scatter<<<(ET + 255) / 256, 256, 0, stream>>>(ei, pos, pse);
    k_lale<<<1, 32, 0, stream>>>(gsum, PB, cB, lale);
    for (int l = 0; l < LL; l++) {
        k_xh<<<Nn / 16, 512, 0, stream>>>(h, glw + (size_t)l * 65536, Bs + l * 512, Bd + l * 512,
                                          xh, als, ald);
        k_agg<<<Nn / 4, 256, 0, stream>>>(pse, seg, als, ald, aleT + (size_t)l * Ee * 4,
                                          lale + l * 4, xh,
                                          gb + l * 128, lnsc + l * 128, lnbi + l * 128, h);
    }
    k_out<<<Nn / 8, 256, 0, stream>>>(h, ow, ob, out);
}

// Round 6
// 656.382 us; speedup vs baseline: 1.7485x; 1.2325x over previous
//
#include <hip/hip_runtime.h>
#include <hip/hip_bf16.h>
#include <math.h>

#define Nn 10000
#define Ee 160000
#define ET 170000   // Ee + Nn (self loops)
#define LL 6

__device__ __forceinline__ unsigned short f2bf(float v) {
    unsigned int b = __float_as_uint(v);
    b += 0x7fffu + ((b >> 16) & 1u);   // RNE
    return (unsigned short)(b >> 16);
}

// ---------------- node embedding: h = x @ node_w + node_b ----------------
__global__ void k_node_embed(const float* __restrict__ x, const float* __restrict__ nw,
                             const float* __restrict__ nb, float* __restrict__ h) {
    int idx = blockIdx.x * 256 + threadIdx.x;
    if (idx >= Nn * 128) return;
    int n = idx >> 7, c = idx & 127;
    const float* xr = x + (size_t)n * 8;
    float acc = nb[c];
#pragma unroll
    for (int k = 0; k < 8; k++) acc += xr[k] * nw[k * 128 + c];
    h[idx] = acc;
}

// ---------------- small precompute: E1[128][8] = {M1[0..3][k], d1[k], 0,0,0} ----------------
__global__ void k_small(const float* __restrict__ vnfc, const float* __restrict__ vw,
                        const float* __restrict__ vb, const float* __restrict__ eab,
                        const float* __restrict__ a1w, const float* __restrict__ a1b,
                        const float* __restrict__ eaw, float* __restrict__ E1) {
    __shared__ float vr[128];
    __shared__ float sM1[512];
    __shared__ float sd1[128];
    int t = threadIdx.x;   // 512
    if (t < 128) {
        float a = vb[t];
#pragma unroll
        for (int k = 0; k < 6; k++) a += vnfc[k] * vw[k * 128 + t];
        vr[t] = a;
    }
    __syncthreads();
    if (t < 128) {
        float a = a1b[t];
        for (int k = 0; k < 128; k++) a += eab[k] * a1w[k * 128 + t];
        for (int k = 0; k < 128; k++) a += vr[k] * a1w[(128 + k) * 128 + t];
        sd1[t] = a;
    }
    {
        int r = t >> 7, j = t & 127;
        float a = 0.f;
        for (int k = 0; k < 128; k++) a += eaw[r * 128 + k] * a1w[k * 128 + j];
        sM1[r * 128 + j] = a;
    }
    __syncthreads();
    if (t < 128) {
        E1[t * 8 + 0] = sM1[t];
        E1[t * 8 + 1] = sM1[128 + t];
        E1[t * 8 + 2] = sM1[256 + t];
        E1[t * 8 + 3] = sM1[384 + t];
        E1[t * 8 + 4] = sd1[t];
        E1[t * 8 + 5] = 0.f; E1[t * 8 + 6] = 0.f; E1[t * 8 + 7] = 0.f;
    }
}

// ---------------- B matrices: Bs/Bd/Be [L][128][4] ----------------
__global__ void k_bmat(const float* __restrict__ glw, const float* __restrict__ gas,
                       const float* __restrict__ gad, const float* __restrict__ glew,
                       const float* __restrict__ gae, float* __restrict__ Bs,
                       float* __restrict__ Bd, float* __restrict__ Be) {
    int idx = blockIdx.x * 256 + threadIdx.x;
    if (idx >= LL * 128 * 4) return;
    int hh = idx & 3, k = (idx >> 2) & 127, l = idx >> 9;
    const float* lwp = glw  + (size_t)l * 65536 + k * 512 + hh * 128;
    const float* lep = glew + (size_t)l * 65536 + k * 512 + hh * 128;
    const float* sp = gas + l * 512 + hh * 128;
    const float* dp = gad + l * 512 + hh * 128;
    const float* ep = gae + l * 512 + hh * 128;
    float s1 = 0, s2 = 0, s3 = 0;
    for (int c = 0; c < 128; c++) {
        float lv = lwp[c];
        s1 += lv * sp[c];
        s2 += lv * dp[c];
        s3 += lep[c] * ep[c];
    }
    Bs[idx] = s1; Bd[idx] = s2; Be[idx] = s3;
}

// ---------------- PB[4][24], cB[24]: fold ea_proj through Be ----------------
__global__ void k_pb(const float* __restrict__ eaw, const float* __restrict__ eab,
                     const float* __restrict__ Be, float* __restrict__ PB,
                     float* __restrict__ cB) {
    int t = threadIdx.x;
    if (t >= 24) return;
    int l = t >> 2, hh = t & 3;
    const float* bp = Be + l * 512 + hh;
    float s0 = 0, s1 = 0, s2 = 0, s3 = 0, sc = 0;
    for (int k = 0; k < 128; k++) {
        float bv = bp[k * 4];
        s0 += eaw[0 * 128 + k] * bv;
        s1 += eaw[1 * 128 + k] * bv;
        s2 += eaw[2 * 128 + k] * bv;
        s3 += eaw[3 * 128 + k] * bv;
        sc += eab[k] * bv;
    }
    PB[0 * 24 + t] = s0; PB[1 * 24 + t] = s1;
    PB[2 * 24 + t] = s2; PB[3 * 24 + t] = s3;
    cB[t] = sc;
}

// ---- edge gate MLP: LDS weights; 256 edges/block, 4/lane, 4 waves split the 64 j ----
__global__ __launch_bounds__(256) void k_edge(
    const float* __restrict__ ea, const float* __restrict__ E1,
    const float* __restrict__ a2w, const float* __restrict__ a2b,
    const float* __restrict__ a3w, const float* __restrict__ a3b,
    const float* __restrict__ PB, const float* __restrict__ cB,
    float* __restrict__ aleT, float* __restrict__ gsum) {
    __shared__ float sw2[128 * 64];   // 32 KB, [k][j]
    __shared__ float4 sM[128];
    __shared__ float sD[128];
    __shared__ float prs[4][256];
    __shared__ float gsh[256];
    int t = threadIdx.x;
    int lane = t & 63;
    int p = t >> 6;
    int ps = __builtin_amdgcn_readfirstlane(p);
    for (int z = t; z < 2048; z += 256) ((float4*)sw2)[z] = ((const float4*)a2w)[z];
    if (t < 128) { sM[t] = *(const float4*)(E1 + t * 8); sD[t] = E1[t * 8 + 4]; }
    __syncthreads();
    int eb = blockIdx.x * 256 + lane;
    float4 ev[4];
#pragma unroll
    for (int r = 0; r < 4; r++) ev[r] = *(const float4*)(ea + (size_t)(eb + r * 64) * 4);
    float acc[4][16];
#pragma unroll
    for (int j = 0; j < 16; j++) {
        float b = a2b[ps * 16 + j];
#pragma unroll
        for (int r = 0; r < 4; r++) acc[r][j] = b;
    }
    const float* w2base = sw2 + ps * 16;
    for (int k = 0; k < 128; k++) {
        float4 m = sM[k];
        float dk = sD[k];
        float xx[4];
#pragma unroll
        for (int r = 0; r < 4; r++)
            xx[r] = fmaxf(dk + ev[r].x * m.x + ev[r].y * m.y + ev[r].z * m.z + ev[r].w * m.w, 0.f);
        const float* w2r = w2base + k * 64;
#pragma unroll
        for (int j4 = 0; j4 < 4; j4++) {
            float4 wv = *(const float4*)(w2r + j4 * 4);
#pragma unroll
            for (int r = 0; r < 4; r++) {
                acc[r][4 * j4 + 0] += xx[r] * wv.x;
                acc[r][4 * j4 + 1] += xx[r] * wv.y;
                acc[r][4 * j4 + 2] += xx[r] * wv.z;
                acc[r][4 * j4 + 3] += xx[r] * wv.w;
            }
        }
    }
#pragma unroll
    for (int r = 0; r < 4; r++) {
        float pr = 0.f;
#pragma unroll
        for (int j = 0; j < 16; j++) pr += fmaxf(acc[r][j], 0.f) * a3w[ps * 16 + j];
        prs[p][r * 64 + lane] = pr;
    }
    __syncthreads();
    if (p == 0) {
        float v0 = 0.f, v1 = 0.f, v2 = 0.f, v3 = 0.f, v4 = 0.f;
#pragma unroll
        for (int rep = 0; rep < 4; rep++) {
            int le = rep * 64 + lane;
            float tot = prs[0][le] + prs[1][le] + prs[2][le] + prs[3][le] + a3b[0];
            float g = 1.f / (1.f + __expf(-tot));
            gsh[le] = g;
            float4 evv = ev[rep];
            v0 += g; v1 += g * evv.x; v2 += g * evv.y; v3 += g * evv.z; v4 += g * evv.w;
        }
#pragma unroll
        for (int d = 32; d > 0; d >>= 1) {
            v0 += __shfl_down(v0, d); v1 += __shfl_down(v1, d); v2 += __shfl_down(v2, d);
            v3 += __shfl_down(v3, d); v4 += __shfl_down(v4, d);
        }
        if (lane == 0) {
            atomicAdd(&gsum[0], v0); atomicAdd(&gsum[1], v1); atomicAdd(&gsum[2], v2);
            atomicAdd(&gsum[3], v3); atomicAdd(&gsum[4], v4);
        }
    }
    __syncthreads();
#pragma unroll
    for (int rep = 0; rep < 2; rep++) {
        int i4 = (rep == 0) ? ps : (ps < 2 ? ps + 4 : -1);
        if (i4 >= 0) {
            float4 c  = *(const float4*)(cB + i4 * 4);
            float4 p0 = *(const float4*)(PB + 0 * 24 + i4 * 4);
            float4 p1 = *(const float4*)(PB + 1 * 24 + i4 * 4);
            float4 p2 = *(const float4*)(PB + 2 * 24 + i4 * 4);
            float4 p3 = *(const float4*)(PB + 3 * 24 + i4 * 4);
#pragma unroll
            for (int r = 0; r < 4; r++) {
                float g = gsh[r * 64 + lane];
                float4 evv = ev[r];
                float4 o;
                o.x = g * (c.x + evv.x * p0.x + evv.y * p1.x + evv.z * p2.x + evv.w * p3.x);
                o.y = g * (c.y + evv.x * p0.y + evv.y * p1.y + evv.z * p2.y + evv.w * p3.y);
                o.z = g * (c.z + evv.x * p0.z + evv.y * p1.z + evv.z * p2.z + evv.w * p3.z);
                o.w = g * (c.w + evv.x * p0.w + evv.y * p1.w + evv.z * p2.w + evv.w * p3.w);
                *(float4*)(aleT + (size_t)i4 * Ee * 4 + (size_t)(eb + r * 64) * 4) = o;
            }
        }
    }
}

// ---------------- loop-edge al_e from G,S sums ----------------
__global__ void k_lale(const float* __restrict__ gsum, const float* __restrict__ PB,
                       const float* __restrict__ cB, float* __restrict__ lale) {
    int t = threadIdx.x;
    if (t >= 24) return;
    float s = gsum[0] * cB[t] + gsum[1] * PB[t] + gsum[2] * PB[24 + t]
            + gsum[3] * PB[48 + t] + gsum[4] * PB[72 + t];
    lale[t] = s * (1.0f / Ee);
}

// ---------------- counting sort by dst: hist / scan / scatter ----------------
__global__ void k_hist(const int* __restrict__ ei, int* __restrict__ hist) {
    int i = blockIdx.x * 256 + threadIdx.x;
    if (i >= ET) return;
    int d = (i < Ee) ? ei[Ee + i] : (i - Ee);
    atomicAdd(&hist[d], 1);
}

__global__ __launch_bounds__(1024) void k_scan(const int* __restrict__ hist,
                                               int* __restrict__ seg, int* __restrict__ pos) {
    __shared__ int wsums[16];
    __shared__ int carry_s;
    int t = threadIdx.x;
    int lane = t & 63, wid = t >> 6;
    if (t == 0) { carry_s = 0; seg[0] = 0; }
    __syncthreads();
    for (int base = 0; base < Nn; base += 1024) {
        int idx = base + t;
        int v = (idx < Nn) ? hist[idx] : 0;
        int sc = v;
#pragma unroll
        for (int d = 1; d < 64; d <<= 1) {
            int up = __shfl_up(sc, d);
            if (lane >= d) sc += up;
        }
        if (lane == 63) wsums[wid] = sc;
        __syncthreads();
        if (wid == 0) {
            int wv = (lane < 16) ? wsums[lane] : 0;
            int wsc = wv;
#pragma unroll
            for (int d = 1; d < 16; d <<= 1) {
                int up = __shfl_up(wsc, d);
                if (lane >= d) wsc += up;
            }
            if (lane < 16) wsums[lane] = wsc - wv;
        }
        __syncthreads();
        int carry = carry_s;
        int inc = sc + wsums[wid] + carry;
        if (idx < Nn) { seg[idx + 1] = inc; pos[idx] = inc - v; }
        __syncthreads();
        if (t == 1023) carry_s = inc;
        __syncthreads();
    }
}

__global__ void k_scatter(const int* __restrict__ ei, int* __restrict__ pos,
                          int2* __restrict__ pse, int* __restrict__ pdst) {
    int i = blockIdx.x * 256 + threadIdx.x;
    if (i >= ET) return;
    int s, d;
    if (i < Ee) { s = ei[i]; d = ei[Ee + i]; } else { s = d = i - Ee; }
    int idx = atomicAdd(&pos[d], 1);
    pse[idx] = make_int2(s, i);
    pdst[idx] = d;
}

// ---------------- per-layer: xh(bf16) = h @ lw ; als/ald = h @ Bs/Bd ----------------
__global__ __launch_bounds__(512) void k_xh(
    const float* __restrict__ h, const float* __restrict__ lw,
    const float* __restrict__ Bs, const float* __restrict__ Bd,
    unsigned short* __restrict__ xhb, float* __restrict__ als, float* __restrict__ ald) {
    __shared__ float4 hs4[16][32];
    int t = threadIdx.x;   // 512
    int n0 = blockIdx.x * 16;
    {
        int i = t >> 5, kb = t & 31;
        hs4[i][kb] = *(const float4*)(h + (size_t)(n0 + i) * 128 + 4 * kb);
    }
    __syncthreads();
    int g = t >> 7;              // 0..3 -> rows g*4..g*4+3
    int c4 = (t & 127) * 4;
    const float* lwc = lw + c4;
    float4 acc[4];
#pragma unroll
    for (int i = 0; i < 4; i++) acc[i] = make_float4(0.f, 0.f, 0.f, 0.f);
    for (int kb = 0; kb < 32; kb++) {
        float4 w0 = *(const float4*)(lwc + (size_t)(4 * kb + 0) * 512);
        float4 w1 = *(const float4*)(lwc + (size_t)(4 * kb + 1) * 512);
        float4 w2 = *(const float4*)(lwc + (size_t)(4 * kb + 2) * 512);
        float4 w3 = *(const float4*)(lwc + (size_t)(4 * kb + 3) * 512);
#pragma unroll
        for (int i = 0; i < 4; i++) {
            float4 hv = hs4[g * 4 + i][kb];
            acc[i].x += hv.x * w0.x + hv.y * w1.x + hv.z * w2.x + hv.w * w3.x;
            acc[i].y += hv.x * w0.y + hv.y * w1.y + hv.z * w2.y + hv.w * w3.y;
            acc[i].z += hv.x * w0.z + hv.y * w1.z + hv.z * w2.z + hv.w * w3.z;
            acc[i].w += hv.x * w0.w + hv.y * w1.w + hv.z * w2.w + hv.w * w3.w;
        }
    }
#pragma unroll
    for (int i = 0; i < 4; i++) {
        ushort4 st;
        st.x = f2bf(acc[i].x); st.y = f2bf(acc[i].y);
        st.z = f2bf(acc[i].z); st.w = f2bf(acc[i].w);
        *(ushort4*)(xhb + (size_t)(n0 + g * 4 + i) * 512 + c4) = st;
    }
    if (t < 64) {
        int i = t >> 2, hh = t & 3;
        float s1 = 0, s2 = 0;
        for (int kb = 0; kb < 32; kb++) {
            float4 hv = hs4[i][kb];
            s1 += hv.x * Bs[(4 * kb + 0) * 4 + hh] + hv.y * Bs[(4 * kb + 1) * 4 + hh]
                + hv.z * Bs[(4 * kb + 2) * 4 + hh] + hv.w * Bs[(4 * kb + 3) * 4 + hh];
            s2 += hv.x * Bd[(4 * kb + 0) * 4 + hh] + hv.y * Bd[(4 * kb + 1) * 4 + hh]
                + hv.z * Bd[(4 * kb + 2) * 4 + hh] + hv.w * Bd[(4 * kb + 3) * 4 + hh];
        }
        als[(n0 + i) * 4 + hh] = s1;
        ald[(n0 + i) * 4 + hh] = s2;
    }
}

// ---- per-layer: finished logits in sorted order = leaky(als[src]+ald[dst]+al_e) ----
__global__ void k_alpha(const int2* __restrict__ pse, const int* __restrict__ pdst,
                        const float* __restrict__ als, const float* __restrict__ ald,
                        const float* __restrict__ aleT_l, const float* __restrict__ lale_l,
                        float* __restrict__ alphap) {
    int i = blockIdx.x * 256 + threadIdx.x;
    if (i >= ET) return;
    int2 se = pse[i];
    int d = pdst[i];
    float4 a = *(const float4*)(als + (size_t)se.x * 4);
    float4 ad = *(const float4*)(ald + (size_t)d * 4);
    float4 b = se.y < Ee ? *(const float4*)(aleT_l + (size_t)se.y * 4)
                         : *(const float4*)lale_l;
    float4 o;
    o.x = a.x + ad.x + b.x; o.y = a.y + ad.y + b.y;
    o.z = a.z + ad.z + b.z; o.w = a.w + ad.w + b.w;
    o.x = o.x > 0.f ? o.x : 0.2f * o.x;
    o.y = o.y > 0.f ? o.y : 0.2f * o.y;
    o.z = o.z > 0.f ? o.z : 0.2f * o.z;
    o.w = o.w > 0.f ? o.w : 0.2f * o.w;
    *(float4*)(alphap + (size_t)i * 4) = o;
}

// ---- per-layer: wave per node; sequential alpha stream + bf16 xh gather + LN ----
__global__ __launch_bounds__(256) void k_agg(
    const float* __restrict__ alphap, const int2* __restrict__ pse,
    const int* __restrict__ seg, const unsigned short* __restrict__ xhb,
    const float* __restrict__ bias, const float* __restrict__ lnsc,
    const float* __restrict__ lnbi, float* __restrict__ hio) {
    __shared__ float wgtS[4][256];
    __shared__ int srcS[4][64];
    int t = threadIdx.x;
    int lane = t & 63;
    int w = t >> 6;
    int n = blockIdx.x * 4 + w;
    int start = seg[n], end = seg[n + 1];
    // ---- phase 1: online (max, sumexp); lane -> head lane&3, edges strided 16 ----
    int h1 = lane & 3;
    float m = -INFINITY, ss = 0.f;
    for (int i = start + (lane >> 2); i < end; i += 16) {
        float av = alphap[(size_t)i * 4 + h1];
        if (av > m) { ss = ss * __expf(m - av) + 1.f; m = av; }
        else ss += __expf(av - m);
    }
#pragma unroll
    for (int d = 4; d <= 32; d <<= 1) {
        float mo = __shfl_xor(m, d), so = __shfl_xor(ss, d);
        float mm = fmaxf(m, mo);
        float sv = 0.f;
        if (m > -INFINITY) sv += ss * __expf(m - mm);
        if (mo > -INFINITY) sv += so * __expf(mo - mm);
        m = mm; ss = sv;
    }
    float mh0 = __shfl(m, 0), mh1 = __shfl(m, 1), mh2 = __shfl(m, 2), mh3 = __shfl(m, 3);
    float iv0 = 1.f / (__shfl(ss, 0) + 1e-16f), iv1 = 1.f / (__shfl(ss, 1) + 1e-16f);
    float iv2 = 1.f / (__shfl(ss, 2) + 1e-16f), iv3 = 1.f / (__shfl(ss, 3) + 1e-16f);
    int hp = lane >> 4;      // head owned in gather
    int c8 = lane * 8;       // channels [lane*8, lane*8+8) of 512
    float4 acc0 = make_float4(0.f, 0.f, 0.f, 0.f);
    float4 acc1 = make_float4(0.f, 0.f, 0.f, 0.f);
    for (int cb = start; cb < end; cb += 64) {
        int cnt = min(64, end - cb);
        if (lane < cnt) {
            float4 al = *(const float4*)(alphap + (size_t)(cb + lane) * 4);
            float4 wg;
            wg.x = __expf(al.x - mh0) * iv0;
            wg.y = __expf(al.y - mh1) * iv1;
            wg.z = __expf(al.z - mh2) * iv2;
            wg.w = __expf(al.w - mh3) * iv3;
            *(float4*)&wgtS[w][lane * 4] = wg;
            srcS[w][lane] = pse[cb + lane].x;
        }
        int i2 = 0;
        for (; i2 + 2 <= cnt; i2 += 2) {
            int s0 = srcS[w][i2], s1 = srcS[w][i2 + 1];
            float wg0 = wgtS[w][i2 * 4 + hp], wg1 = wgtS[w][i2 * 4 + 4 + hp];
            uint4 u0 = *(const uint4*)(xhb + (size_t)s0 * 512 + c8);
            uint4 u1 = *(const uint4*)(xhb + (size_t)s1 * 512 + c8);
            acc0.x += wg0 * __uint_as_float(u0.x << 16) + wg1 * __uint_as_float(u1.x << 16);
            acc0.y += wg0 * __uint_as_float(u0.x & 0xffff0000u) + wg1 * __uint_as_float(u1.x & 0xffff0000u);
            acc0.z += wg0 * __uint_as_float(u0.y << 16) + wg1 * __uint_as_float(u1.y << 16);
            acc0.w += wg0 * __uint_as_float(u0.y & 0xffff0000u) + wg1 * __uint_as_float(u1.y & 0xffff0000u);
            acc1.x += wg0 * __uint_as_float(u0.z << 16) + wg1 * __uint_as_float(u1.z << 16);
            acc1.y += wg0 * __uint_as_float(u0.z & 0xffff0000u) + wg1 * __uint_as_float(u1.z & 0xffff0000u);
            acc1.z += wg0 * __uint_as_float(u0.w << 16) + wg1 * __uint_as_float(u1.w << 16);
            acc1.w += wg0 * __uint_as_float(u0.w & 0xffff0000u) + wg1 * __uint_as_float(u1.w & 0xffff0000u);
        }
        if (i2 < cnt) {
            int s0 = srcS[w][i2];
            float wg0 = wgtS[w][i2 * 4 + hp];
            uint4 u0 = *(const uint4*)(xhb + (size_t)s0 * 512 + c8);
            acc0.x += wg0 * __uint_as_float(u0.x << 16);
            acc0.y += wg0 * __uint_as_float(u0.x & 0xffff0000u);
            acc0.z += wg0 * __uint_as_float(u0.y << 16);
            acc0.w += wg0 * __uint_as_float(u0.y & 0xffff0000u);
            acc1.x += wg0 * __uint_as_float(u0.z << 16);
            acc1.y += wg0 * __uint_as_float(u0.z & 0xffff0000u);
            acc1.z += wg0 * __uint_as_float(u0.w << 16);
            acc1.w += wg0 * __uint_as_float(u0.w & 0xffff0000u);
        }
    }
    // ---- head mean: xor 16,32 sums the 4 heads for channel slice (lane&15)*8 ----
#pragma unroll
    for (int d = 16; d <= 32; d <<= 1) {
        acc0.x += __shfl_xor(acc0.x, d); acc0.y += __shfl_xor(acc0.y, d);
        acc0.z += __shfl_xor(acc0.z, d); acc0.w += __shfl_xor(acc0.w, d);
        acc1.x += __shfl_xor(acc1.x, d); acc1.y += __shfl_xor(acc1.y, d);
        acc1.z += __shfl_xor(acc1.z, d); acc1.w += __shfl_xor(acc1.w, d);
    }
    int cc = (lane & 15) * 8;
    float4 b0 = *(const float4*)(bias + cc), b1 = *(const float4*)(bias + cc + 4);
    float4 h0 = *(const float4*)(hio + (size_t)n * 128 + cc);
    float4 h1v = *(const float4*)(hio + (size_t)n * 128 + cc + 4);
    float4 v0, v1;
    v0.x = h0.x + fmaxf(0.25f * acc0.x + b0.x, 0.f);
    v0.y = h0.y + fmaxf(0.25f * acc0.y + b0.y, 0.f);
    v0.z = h0.z + fmaxf(0.25f * acc0.z + b0.z, 0.f);
    v0.w = h0.w + fmaxf(0.25f * acc0.w + b0.w, 0.f);
    v1.x = h1v.x + fmaxf(0.25f * acc1.x + b1.x, 0.f);
    v1.y = h1v.y + fmaxf(0.25f * acc1.y + b1.y, 0.f);
    v1.z = h1v.z + fmaxf(0.25f * acc1.z + b1.z, 0.f);
    v1.w = h1v.w + fmaxf(0.25f * acc1.w + b1.w, 0.f);
    float s1 = v0.x + v0.y + v0.z + v0.w + v1.x + v1.y + v1.z + v1.w;
    float s2 = v0.x * v0.x + v0.y * v0.y + v0.z * v0.z + v0.w * v0.w
             + v1.x * v1.x + v1.y * v1.y + v1.z * v1.z + v1.w * v1.w;
#pragma unroll
    for (int d = 1; d <= 8; d <<= 1) {
        s1 += __shfl_xor(s1, d); s2 += __shfl_xor(s2, d);
    }
    float mean = s1 * (1.f / 128.f);
    float var = s2 * (1.f / 128.f) - mean * mean;
    float rinv = rsqrtf(var + 1e-5f);
    if (lane < 16) {
        float4 ls0 = *(const float4*)(lnsc + cc), ls1 = *(const float4*)(lnsc + cc + 4);
        float4 lb0 = *(const float4*)(lnbi + cc), lb1 = *(const float4*)(lnbi + cc + 4);
        float4 o0, o1;
        o0.x = (v0.x - mean) * rinv * ls0.x + lb0.x;
        o0.y = (v0.y - mean) * rinv * ls0.y + lb0.y;
        o0.z = (v0.z - mean) * rinv * ls0.z + lb0.z;
        o0.w = (v0.w - mean) * rinv * ls0.w + lb0.w;
        o1.x = (v1.x - mean) * rinv * ls1.x + lb1.x;
        o1.y = (v1.y - mean) * rinv * ls1.y + lb1.y;
        o1.z = (v1.z - mean) * rinv * ls1.z + lb1.z;
        o1.w = (v1.w - mean) * rinv * ls1.w + lb1.w;
        *(float4*)(hio + (size_t)n * 128 + cc) = o0;
        *(float4*)(hio + (size_t)n * 128 + cc + 4) = o1;
    }
}

// ---------------- output projection ----------------
__global__ __launch_bounds__(256) void k_out(
    const float* __restrict__ h, const float* __restrict__ ow,
    const float* __restrict__ ob, float* __restrict__ out) {
    __shared__ float4 hs4[8][32];
    int t = threadIdx.x;
    int n0 = blockIdx.x * 8;
    if (t < 256) {
        int i = t >> 5, kb = t & 31;
        hs4[i][kb] = *(const float4*)(h + (size_t)(n0 + i) * 128 + 4 * kb);
    }
    __syncthreads();
    float acc[8] = {0, 0, 0, 0, 0, 0, 0, 0};
    for (int kb = 0; kb < 32; kb++) {
        float w0 = ow[(4 * kb + 0) * 256 + t];
        float w1 = ow[(4 * kb + 1) * 256 + t];
        float w2 = ow[(4 * kb + 2) * 256 + t];
        float w3 = ow[(4 * kb + 3) * 256 + t];
#pragma unroll
        for (int i = 0; i < 8; i++) {
            float4 hv = hs4[i][kb];
            acc[i] += hv.x * w0 + hv.y * w1 + hv.z * w2 + hv.w * w3;
        }
    }
    float b = ob[t];
#pragma unroll
    for (int i = 0; i < 8; i++) out[(size_t)(n0 + i) * 256 + t] = acc[i] + b;
}

extern "C" void kernel_launch(void* const* d_in, const int* in_sizes, int n_in,
                              void* d_out, int out_size, void* d_ws, size_t ws_size,
                              hipStream_t stream) {
    const float* x    = (const float*)d_in[0];
    const int*   ei   = (const int*)d_in[1];
    const float* ea   = (const float*)d_in[2];
    const float* vnfc = (const float*)d_in[3];
    const float* nw   = (const float*)d_in[4];
    const float* nb   = (const float*)d_in[5];
    const float* eaw  = (const float*)d_in[6];
    const float* eab  = (const float*)d_in[7];
    const float* vw   = (const float*)d_in[8];
    const float* vb   = (const float*)d_in[9];
    const float* a1w  = (const float*)d_in[10];
    const float* a1b  = (const float*)d_in[11];
    const float* a2w  = (const float*)d_in[12];
    const float* a2b  = (const float*)d_in[13];
    const float* a3w  = (const float*)d_in[14];
    const float* a3b  = (const float*)d_in[15];
    const float* glw  = (const float*)d_in[16];
    const float* gas  = (const float*)d_in[17];
    const float* gad  = (const float*)d_in[18];
    const float* glew = (const float*)d_in[19];
    const float* gae  = (const float*)d_in[20];
    const float* gb   = (const float*)d_in[21];
    const float* lnsc = (const float*)d_in[22];
    const float* lnbi = (const float*)d_in[23];
    const float* ow   = (const float*)d_in[24];
    const float* ob   = (const float*)d_in[25];
    float* out = (float*)d_out;

    char* w = (char*)d_ws;
    size_t o = 0;
    auto allocf = [&](size_t cnt) { float* p = (float*)(w + o); o += ((cnt * 4 + 255) / 256) * 256; return p; };
    auto alloci = [&](size_t cnt) { int* p = (int*)(w + o); o += ((cnt * 4 + 255) / 256) * 256; return p; };
    auto allocu = [&](size_t cnt) { unsigned short* p = (unsigned short*)(w + o); o += ((cnt * 2 + 255) / 256) * 256; return p; };
    float* h      = allocf((size_t)Nn * 128);
    unsigned short* xhb = allocu((size_t)Nn * 512);
    float* als    = allocf((size_t)Nn * 4);
    float* ald    = allocf((size_t)Nn * 4);
    float* aleT   = allocf((size_t)LL * Ee * 4);
    float* alphap = allocf((size_t)ET * 4);
    float* Bs     = allocf(3072);
    float* Bd     = allocf(3072);
    float* Be     = allocf(3072);
    float* E1     = allocf(1024);
    float* PB     = allocf(96);
    float* cB     = allocf(24);
    float* gsum   = allocf(8);
    float* lale   = allocf(32);
    int* seg  = alloci(Nn + 1);
    int* hist = alloci(Nn);
    int* pos  = alloci(Nn);
    int2* pse = (int2*)alloci((size_t)ET * 2);
    int* pdst = alloci(ET);

    hipMemsetAsync(hist, 0, Nn * sizeof(int), stream);
    hipMemsetAsync(gsum, 0, 8 * sizeof(float), stream);

    k_node_embed<<<(Nn * 128 + 255) / 256, 256, 0, stream>>>(x, nw, nb, h);
    k_small<<<1, 512, 0, stream>>>(vnfc, vw, vb, eab, a1w, a1b, eaw, E1);
    k_bmat<<<(LL * 128 * 4 + 255) / 256, 256, 0, stream>>>(glw, gas, gad, glew, gae, Bs, Bd, Be);
    k_pb<<<1, 32, 0, stream>>>(eaw, eab, Be, PB, cB);
    k_edge<<<Ee / 256, 256, 0, stream>>>(ea, E1, a2w, a2b, a3w, a3b, PB, cB, aleT, gsum);
    k_hist<<<(ET + 255) / 256, 256, 0, stream>>>(ei, hist);
    k_scan<<<1, 1024, 0, stream>>>(hist, seg, pos);
    k_scatter<<<(ET + 255) / 256, 256, 0, stream>>>(ei, pos, pse, pdst);
    k_lale<<<1, 32, 0, stream>>>(gsum, PB, cB, lale);
    for (int l = 0; l < LL; l++) {
        k_xh<<<Nn / 16, 512, 0, stream>>>(h, glw + (size_t)l * 65536, Bs + l * 512, Bd + l * 512,
                                          xhb, als, ald);
        k_alpha<<<(ET + 255) / 256, 256, 0, stream>>>(pse, pdst, als, ald,
                                                      aleT + (size_t)l * Ee * 4, lale + l * 4, alphap);
        k_agg<<<Nn / 4, 256, 0, stream>>>(alphap, pse, seg, xhb,
                                          gb + l * 128, lnsc + l * 128, lnbi + l * 128, h);
    }
    k_out<<<Nn / 8, 256, 0, stream>>>(h, ow, ob, out);
}